// Round 1
// baseline (707.057 us; speedup 1.0000x reference)
//
#include <hip/hip_runtime.h>

// Problem constants (match reference): N=100000 nodes, E=600000 edges,
// DIN=768, H=128, G=100. n_tool=99000, n_query=1000.
// Output layout (flat, f32): tool_logits[99000] | query_logits[1000] | tool_batch_index[99000] (as float)

#define HDIM 128

// ---------------- CSR build ----------------

__global__ __launch_bounds__(256) void k_count(const int* __restrict__ dst,
                                               int* __restrict__ degi, int E) {
  int g = blockIdx.x * 256 + threadIdx.x;
  if (g < E) atomicAdd(&degi[dst[g]], 1);
}

__global__ __launch_bounds__(256) void k_dinv(const int* __restrict__ degi,
                                              float* __restrict__ dinv, int N) {
  int g = blockIdx.x * 256 + threadIdx.x;
  if (g < N) dinv[g] = rsqrtf((float)(degi[g] + 1));  // +1 self-loop; deg>0 always
}

__global__ __launch_bounds__(256) void k_scan1(const int* __restrict__ in,
                                               int* __restrict__ out,
                                               int* __restrict__ bsum, int n) {
  __shared__ int s[256];
  int t = threadIdx.x, g = blockIdx.x * 256 + t;
  int v = (g < n) ? in[g] : 0;
  s[t] = v;
  for (int off = 1; off < 256; off <<= 1) {
    __syncthreads();
    int x = (t >= off) ? s[t - off] : 0;
    __syncthreads();
    s[t] += x;
  }
  if (g < n) out[g] = s[t] - v;          // exclusive within block
  if (t == 255) bsum[blockIdx.x] = s[255];
}

__global__ __launch_bounds__(512) void k_scan2(int* __restrict__ bsum, int nb) {
  // nb <= 512 required (N=100000 -> 391 blocks)
  __shared__ int s[512];
  int t = threadIdx.x;
  int v = (t < nb) ? bsum[t] : 0;
  s[t] = v;
  for (int off = 1; off < 512; off <<= 1) {
    __syncthreads();
    int x = (t >= off) ? s[t - off] : 0;
    __syncthreads();
    s[t] += x;
  }
  if (t < nb) bsum[t] = s[t] - v;        // exclusive block offsets
}

__global__ __launch_bounds__(256) void k_scan3(int* __restrict__ row_start,
                                               const int* __restrict__ bsum,
                                               int n, int total) {
  int g = blockIdx.x * 256 + threadIdx.x;
  if (g < n) row_start[g] += bsum[g >> 8];
  if (g == 0) row_start[n] = total;
}

__global__ __launch_bounds__(256) void k_fill(const int* __restrict__ src,
                                              const int* __restrict__ dst,
                                              const int* __restrict__ row_start,
                                              int* __restrict__ fill,
                                              const float* __restrict__ dinv,
                                              int* __restrict__ csr_src,
                                              float* __restrict__ csr_norm, int E) {
  int g = blockIdx.x * 256 + threadIdx.x;
  if (g < E) {
    int s = src[g], d = dst[g];
    int p = atomicAdd(&fill[d], 1);
    int o = row_start[d] + p;
    csr_src[o] = s;
    csr_norm[o] = dinv[s] * dinv[d];
  }
}

// ---------------- f32 GEMM: C[M,128] = A[M,K] @ B[K,128] (+bias) ----------------
// Tile 128x128, BK=32, 256 threads, 8x8 micro-tile per thread.

template <int K>
__global__ __launch_bounds__(256) void k_gemm(const float* __restrict__ A,
                                              const float* __restrict__ B,
                                              const float* __restrict__ bias,
                                              float* __restrict__ C, int M) {
  __shared__ float As[32][136];   // transposed A tile, stride 136 (16B-aligned rows)
  __shared__ float Bs[32][128];
  const int tid = threadIdx.x;
  const int m0 = blockIdx.x * 128;
  const int cx = tid & 15;        // 16 col groups * 8 cols
  const int ry = tid >> 4;        // 16 row groups * 8 rows

  float acc[8][8];
#pragma unroll
  for (int j = 0; j < 8; ++j)
#pragma unroll
    for (int i = 0; i < 8; ++i) acc[j][i] = 0.f;

  for (int kb = 0; kb < K; kb += 32) {
    // A tile: 128 rows x 32 k = 1024 float4 chunks, 4 per thread (coalesced on k)
#pragma unroll
    for (int i = 0; i < 4; ++i) {
      int c = i * 256 + tid;
      int row = c >> 3, kk = (c & 7) << 2;
      float4 v = make_float4(0.f, 0.f, 0.f, 0.f);
      if (m0 + row < M) v = *(const float4*)&A[(size_t)(m0 + row) * K + kb + kk];
      As[kk + 0][row] = v.x;
      As[kk + 1][row] = v.y;
      As[kk + 2][row] = v.z;
      As[kk + 3][row] = v.w;
    }
    // B tile: 32 x 128 = 1024 float4 chunks, 4 per thread
#pragma unroll
    for (int i = 0; i < 4; ++i) {
      int f = i * 256 + tid;
      int kr = f >> 5, c4 = (f & 31) << 2;
      *(float4*)&Bs[kr][c4] = *(const float4*)&B[(size_t)(kb + kr) * 128 + c4];
    }
    __syncthreads();
#pragma unroll 8
    for (int k = 0; k < 32; ++k) {
      float4 a0 = *(const float4*)&As[k][ry << 3];
      float4 a1 = *(const float4*)&As[k][(ry << 3) + 4];
      float4 b0 = *(const float4*)&Bs[k][cx << 3];
      float4 b1 = *(const float4*)&Bs[k][(cx << 3) + 4];
      float a[8] = {a0.x, a0.y, a0.z, a0.w, a1.x, a1.y, a1.z, a1.w};
      float b[8] = {b0.x, b0.y, b0.z, b0.w, b1.x, b1.y, b1.z, b1.w};
#pragma unroll
      for (int j = 0; j < 8; ++j)
#pragma unroll
        for (int i = 0; i < 8; ++i) acc[j][i] = fmaf(a[j], b[i], acc[j][i]);
    }
    __syncthreads();
  }

  float4 bv0 = make_float4(0.f, 0.f, 0.f, 0.f), bv1 = bv0;
  if (bias) {
    bv0 = *(const float4*)&bias[cx << 3];
    bv1 = *(const float4*)&bias[(cx << 3) + 4];
  }
#pragma unroll
  for (int j = 0; j < 8; ++j) {
    int row = m0 + (ry << 3) + j;
    if (row < M) {
      float4 o0, o1;
      o0.x = acc[j][0] + bv0.x; o0.y = acc[j][1] + bv0.y;
      o0.z = acc[j][2] + bv0.z; o0.w = acc[j][3] + bv0.w;
      o1.x = acc[j][4] + bv1.x; o1.y = acc[j][5] + bv1.y;
      o1.z = acc[j][6] + bv1.z; o1.w = acc[j][7] + bv1.w;
      *(float4*)&C[(size_t)row * HDIM + (cx << 3)] = o0;
      *(float4*)&C[(size_t)row * HDIM + (cx << 3) + 4] = o1;
    }
  }
}

// ---------------- gather + bias + relu + residual (in place on h) ----------------
// One wave per node; lane handles 2 consecutive h dims (float2 = coalesced 512B/row).

__global__ __launch_bounds__(256) void k_gather(const float* __restrict__ m,
                                                float* __restrict__ h,
                                                const int* __restrict__ row_start,
                                                const int* __restrict__ csr_src,
                                                const float* __restrict__ csr_norm,
                                                const float* __restrict__ dinv,
                                                const float* __restrict__ bias, int N) {
  int wid = (blockIdx.x * 256 + threadIdx.x) >> 6;
  int lane = threadIdx.x & 63;
  if (wid >= N) return;
  const float2* m2 = (const float2*)m;
  float di = dinv[wid];
  float sl = di * di;
  float2 mv = m2[(size_t)wid * 64 + lane];
  float ax = mv.x * sl, ay = mv.y * sl;   // self-loop contribution
  int e0 = row_start[wid], e1 = row_start[wid + 1];
  for (int e = e0; e < e1; ++e) {
    int s = csr_src[e];
    float nr = csr_norm[e];
    float2 v = m2[(size_t)s * 64 + lane];
    ax = fmaf(v.x, nr, ax);
    ay = fmaf(v.y, nr, ay);
  }
  float2 bb = ((const float2*)bias)[lane];
  float2* h2 = (float2*)h;
  float2 hv = h2[(size_t)wid * 64 + lane];
  float2 r;
  r.x = fmaxf(ax + bb.x, 0.f) + hv.x;
  r.y = fmaxf(ay + bb.y, 0.f) + hv.y;
  h2[(size_t)wid * 64 + lane] = r;
}

// ---------------- output: logits + batch index ----------------
// One wave per output row; shuffle-reduce the 128-dim dot.

__global__ __launch_bounds__(256) void k_out(const float* __restrict__ h,
                                             const float* __restrict__ Wout,
                                             const float* __restrict__ bout,
                                             const int* __restrict__ tool_idx,
                                             const int* __restrict__ query_idx,
                                             const int* __restrict__ batch_vec,
                                             float* __restrict__ out,
                                             int n_tool, int n_query) {
  int wid = (blockIdx.x * 256 + threadIdx.x) >> 6;
  int lane = threadIdx.x & 63;
  int total = n_tool + n_query;
  if (wid >= total) return;
  int node = (wid < n_tool) ? tool_idx[wid] : query_idx[wid - n_tool];
  float2 w = ((const float2*)Wout)[lane];
  float2 hv = ((const float2*)h)[(size_t)node * 64 + lane];
  float s = hv.x * w.x + hv.y * w.y;
#pragma unroll
  for (int off = 32; off > 0; off >>= 1) s += __shfl_down(s, off);
  if (lane == 0) {
    out[wid] = s + bout[0];
    if (wid < n_tool) out[total + wid] = (float)batch_vec[node];
  }
}

// ---------------- launcher ----------------

extern "C" void kernel_launch(void* const* d_in, const int* in_sizes, int n_in,
                              void* d_out, int out_size, void* d_ws, size_t ws_size,
                              hipStream_t stream) {
  const float* x        = (const float*)d_in[0];
  const int*   edge_src = (const int*)d_in[1];
  const int*   edge_dst = (const int*)d_in[2];
  const int*   batch_vec= (const int*)d_in[3];
  const int*   tool_idx = (const int*)d_in[4];
  const int*   query_idx= (const int*)d_in[5];
  const float* W_align  = (const float*)d_in[6];
  const float* b_align  = (const float*)d_in[7];
  const float* W1       = (const float*)d_in[8];
  const float* b1       = (const float*)d_in[9];
  const float* W2       = (const float*)d_in[10];
  const float* b2       = (const float*)d_in[11];
  const float* W_out    = (const float*)d_in[12];
  const float* b_out    = (const float*)d_in[13];

  const int N   = in_sizes[3];
  const int E   = in_sizes[1];
  const int DIN = in_sizes[0] / N;     // 768
  const int n_tool  = in_sizes[4];
  const int n_query = in_sizes[5];
  (void)DIN; (void)n_in; (void)out_size; (void)ws_size;

  // workspace carve-up (256B aligned)
  char* p = (char*)d_ws;
  auto alloc = [&](size_t bytes) {
    void* r = (void*)p;
    p += (bytes + 255) & ~(size_t)255;
    return r;
  };
  int*   degi      = (int*)alloc((size_t)N * 4);
  float* dinv      = (float*)alloc((size_t)N * 4);
  int*   row_start = (int*)alloc((size_t)(N + 1) * 4);
  int*   fillc     = (int*)alloc((size_t)N * 4);
  int*   csr_src   = (int*)alloc((size_t)E * 4);
  float* csr_norm  = (float*)alloc((size_t)E * 4);
  float* h         = (float*)alloc((size_t)N * HDIM * 4);
  float* m         = (float*)alloc((size_t)N * HDIM * 4);

  hipMemsetAsync(degi, 0, (size_t)N * 4, stream);
  hipMemsetAsync(fillc, 0, (size_t)N * 4, stream);

  const int nblkE = (E + 255) / 256;
  const int nblkN = (N + 255) / 256;   // 391 (<=512 required for scan2)

  k_count<<<nblkE, 256, 0, stream>>>(edge_dst, degi, E);
  k_dinv<<<nblkN, 256, 0, stream>>>(degi, dinv, N);
  k_scan1<<<nblkN, 256, 0, stream>>>(degi, row_start, fillc + 0, N);
  // reuse end of ws for block sums: place after everything via alloc
  // (fillc is needed zeroed for k_fill, so use a dedicated bsum buffer)
  // -- correction: use dedicated buffer
  // (see bsum alloc below)
  // NOTE: the call above is replaced right after bsum allocation.

  int* bsum = (int*)alloc((size_t)1024 * 4);
  // redo scan1 into row_start with proper bsum (previous launch wrote into fillc;
  // re-zero fillc afterwards to keep k_fill correct)
  k_scan1<<<nblkN, 256, 0, stream>>>(degi, row_start, bsum, N);
  hipMemsetAsync(fillc, 0, (size_t)N * 4, stream);
  k_scan2<<<1, 512, 0, stream>>>(bsum, nblkN);
  k_scan3<<<nblkN, 256, 0, stream>>>(row_start, bsum, N, E);
  k_fill<<<nblkE, 256, 0, stream>>>(edge_src, edge_dst, row_start, fillc, dinv,
                                    csr_src, csr_norm, E);

  const int gemmBlocks = (N + 127) / 128;
  // h = x @ W_align + b_align
  k_gemm<768><<<gemmBlocks, 256, 0, stream>>>(x, W_align, b_align, h, N);

  const int waveBlocks = (N * 64 + 255) / 256;   // one wave per node
  // layer 1
  k_gemm<128><<<gemmBlocks, 256, 0, stream>>>(h, W1, nullptr, m, N);
  k_gather<<<waveBlocks, 256, 0, stream>>>(m, h, row_start, csr_src, csr_norm,
                                           dinv, b1, N);
  // layer 2
  k_gemm<128><<<gemmBlocks, 256, 0, stream>>>(h, W2, nullptr, m, N);
  k_gather<<<waveBlocks, 256, 0, stream>>>(m, h, row_start, csr_src, csr_norm,
                                           dinv, b2, N);

  // outputs
  const int outWaves = n_tool + n_query;
  const int outBlocks = (outWaves * 64 + 255) / 256;
  k_out<<<outBlocks, 256, 0, stream>>>(h, W_out, b_out, tool_idx, query_idx,
                                       batch_vec, (float*)d_out, n_tool, n_query);
}

// Round 2
// 439.529 us; speedup vs baseline: 1.6087x; 1.6087x over previous
//
#include <hip/hip_runtime.h>

// QueryAwareGNN: N=100000, E=600000, DIN=768, H=128, G=100.
// Output (flat f32): tool_logits[99000] | query_logits[1000] | tool_batch_index[99000]

#define HDIM 128

typedef short s16x8 __attribute__((ext_vector_type(8)));
typedef unsigned short u16;
typedef unsigned short u16x8 __attribute__((ext_vector_type(8)));
typedef float f32x4 __attribute__((ext_vector_type(4)));

// split f32 into hi/lo bf16 (truncation; lo captures next 8 mantissa bits)
__device__ inline void split2(float f, u16& hi, u16& lo) {
  unsigned u = __builtin_bit_cast(unsigned, f);
  hi = (u16)(u >> 16);
  float fh = __builtin_bit_cast(float, u & 0xFFFF0000u);
  float fl = f - fh;
  lo = (u16)(__builtin_bit_cast(unsigned, fl) >> 16);
}

// ---------------- CSR build ----------------

__global__ __launch_bounds__(256) void k_count(const int* __restrict__ dst,
                                               int* __restrict__ degi, int E) {
  int g = blockIdx.x * 256 + threadIdx.x;
  if (g < E) atomicAdd(&degi[dst[g]], 1);
}

__global__ __launch_bounds__(256) void k_dinv(const int* __restrict__ degi,
                                              float* __restrict__ dinv, int N) {
  int g = blockIdx.x * 256 + threadIdx.x;
  if (g < N) dinv[g] = rsqrtf((float)(degi[g] + 1));  // +1 self-loop
}

__global__ __launch_bounds__(256) void k_scan1(const int* __restrict__ in,
                                               int* __restrict__ out,
                                               int* __restrict__ bsum, int n) {
  __shared__ int s[256];
  int t = threadIdx.x, g = blockIdx.x * 256 + t;
  int v = (g < n) ? in[g] : 0;
  s[t] = v;
  for (int off = 1; off < 256; off <<= 1) {
    __syncthreads();
    int x = (t >= off) ? s[t - off] : 0;
    __syncthreads();
    s[t] += x;
  }
  if (g < n) out[g] = s[t] - v;
  if (t == 255) bsum[blockIdx.x] = s[255];
}

__global__ __launch_bounds__(512) void k_scan2(int* __restrict__ bsum, int nb) {
  __shared__ int s[512];
  int t = threadIdx.x;
  int v = (t < nb) ? bsum[t] : 0;
  s[t] = v;
  for (int off = 1; off < 512; off <<= 1) {
    __syncthreads();
    int x = (t >= off) ? s[t - off] : 0;
    __syncthreads();
    s[t] += x;
  }
  if (t < nb) bsum[t] = s[t] - v;
}

__global__ __launch_bounds__(256) void k_scan3(int* __restrict__ row_start,
                                               const int* __restrict__ bsum,
                                               int n, int total) {
  int g = blockIdx.x * 256 + threadIdx.x;
  if (g < n) row_start[g] += bsum[g >> 8];
  if (g == 0) row_start[n] = total;
}

__global__ __launch_bounds__(256) void k_fill(const int* __restrict__ src,
                                              const int* __restrict__ dst,
                                              const int* __restrict__ row_start,
                                              int* __restrict__ fill,
                                              const float* __restrict__ dinv,
                                              int* __restrict__ csr_src,
                                              float* __restrict__ csr_norm, int E) {
  int g = blockIdx.x * 256 + threadIdx.x;
  if (g < E) {
    int s = src[g], d = dst[g];
    int p = atomicAdd(&fill[d], 1);
    int o = row_start[d] + p;
    csr_src[o] = s;
    csr_norm[o] = dinv[s] * dinv[d];
  }
}

// ---------------- weight pre-split: W[K][128] -> tiled hi/lo bf16 ----------------
// Tiled layout: th[(k/32)][n][k%32]  (each k-block is the exact 8KB LDS image)

__global__ __launch_bounds__(256) void k_split_w(const float* __restrict__ W,
                                                 u16* __restrict__ th,
                                                 u16* __restrict__ tl, int total) {
  int g = blockIdx.x * 256 + threadIdx.x;
  if (g >= total) return;
  int n = g & 127, k = g >> 7;
  u16 h, l;
  split2(W[g], h, l);
  int o = ((k >> 5) << 12) | (n << 5) | (k & 31);
  th[o] = h;
  tl[o] = l;
}

// ---------------- split-bf16 MFMA GEMM: C[M,128] = A[M,K] @ W[K,128] (+bias) ----
// 128x128 tile, BK=32, 256 threads (4 waves 2x2, each wave 64x64 via 16x16x32).

template <int K, bool BIAS>
__global__ __launch_bounds__(256) void k_gemm_bf(const float* __restrict__ A,
                                                 const u16* __restrict__ Bth,
                                                 const u16* __restrict__ Btl,
                                                 const float* __restrict__ bias,
                                                 float* __restrict__ C, int M) {
  __shared__ u16 Ah[128][40];  // pad to 40 (80B rows, 16B aligned)
  __shared__ u16 Al[128][40];
  __shared__ u16 Bh[128][40];  // B stored transposed: Bh[n][k]
  __shared__ u16 Bl[128][40];

  const int t = threadIdx.x;
  const int m0 = blockIdx.x << 7;
  const int lane = t & 63, w = t >> 6;
  const int wm = (w >> 1) << 6, wn = (w & 1) << 6;
  const int fr = lane & 15;          // row (A) / col (B) within fragment
  const int fk = (lane >> 4) << 3;   // k offset within fragment
  const int srow = t >> 1;           // staging: row 0..127
  const int scol = (t & 1) << 4;     // staging: col 0 or 16

  f32x4 acc[4][4] = {};
  const bool valid = (m0 + srow) < M;
  const float* arow = A + (size_t)(m0 + srow) * K + scol;

  for (int kb = 0; kb < K; kb += 32) {
    // ---- A stage: 16 f32 per thread -> split -> 2x ds_write_b128 per half
    f32x4 v0 = {}, v1 = {}, v2 = {}, v3 = {};
    if (valid) {
      const float* ap = arow + kb;
      v0 = *(const f32x4*)(ap + 0);
      v1 = *(const f32x4*)(ap + 4);
      v2 = *(const f32x4*)(ap + 8);
      v3 = *(const f32x4*)(ap + 12);
    }
    u16x8 h0, h1, l0, l1;
#pragma unroll
    for (int j = 0; j < 4; ++j) {
      u16 hh, ll;
      split2(v0[j], hh, ll); h0[j] = hh; l0[j] = ll;
      split2(v1[j], hh, ll); h0[j + 4] = hh; l0[j + 4] = ll;
      split2(v2[j], hh, ll); h1[j] = hh; l1[j] = ll;
      split2(v3[j], hh, ll); h1[j + 4] = hh; l1[j + 4] = ll;
    }
    *(u16x8*)&Ah[srow][scol] = h0;
    *(u16x8*)&Ah[srow][scol + 8] = h1;
    *(u16x8*)&Al[srow][scol] = l0;
    *(u16x8*)&Al[srow][scol + 8] = l1;

    // ---- B stage: coalesced 32B/thread from pre-tiled weights
    {
      const u16* bsrc = Bth + ((size_t)(kb >> 5) << 12) + (t << 4);
      u16x8 p0 = *(const u16x8*)bsrc;
      u16x8 p1 = *(const u16x8*)(bsrc + 8);
      const u16* bsrc2 = Btl + ((size_t)(kb >> 5) << 12) + (t << 4);
      u16x8 q0 = *(const u16x8*)bsrc2;
      u16x8 q1 = *(const u16x8*)(bsrc2 + 8);
      int bn = t >> 1, bseg = (t & 1) << 4;
      *(u16x8*)&Bh[bn][bseg] = p0;
      *(u16x8*)&Bh[bn][bseg + 8] = p1;
      *(u16x8*)&Bl[bn][bseg] = q0;
      *(u16x8*)&Bl[bn][bseg + 8] = q1;
    }
    __syncthreads();

    // ---- fragments + 48 MFMAs
    s16x8 ah[4], al[4], bh[4], bl[4];
#pragma unroll
    for (int i = 0; i < 4; ++i) {
      ah[i] = *(const s16x8*)&Ah[wm + (i << 4) + fr][fk];
      al[i] = *(const s16x8*)&Al[wm + (i << 4) + fr][fk];
      bh[i] = *(const s16x8*)&Bh[wn + (i << 4) + fr][fk];
      bl[i] = *(const s16x8*)&Bl[wn + (i << 4) + fr][fk];
    }
#pragma unroll
    for (int i = 0; i < 4; ++i)
#pragma unroll
      for (int j = 0; j < 4; ++j) {
        acc[i][j] = __builtin_amdgcn_mfma_f32_16x16x32_bf16(ah[i], bh[j], acc[i][j], 0, 0, 0);
        acc[i][j] = __builtin_amdgcn_mfma_f32_16x16x32_bf16(ah[i], bl[j], acc[i][j], 0, 0, 0);
        acc[i][j] = __builtin_amdgcn_mfma_f32_16x16x32_bf16(al[i], bh[j], acc[i][j], 0, 0, 0);
      }
    __syncthreads();
  }

  // ---- epilogue: C/D layout col=lane&15, row=(lane>>4)*4+reg
  const int cr = (lane >> 4) << 2;
#pragma unroll
  for (int i = 0; i < 4; ++i) {
    int mbase = m0 + wm + (i << 4) + cr;
#pragma unroll
    for (int j = 0; j < 4; ++j) {
      int n = wn + (j << 4) + fr;
      float bv = BIAS ? bias[n] : 0.0f;
#pragma unroll
      for (int r = 0; r < 4; ++r)
        if (mbase + r < M) C[(size_t)(mbase + r) * HDIM + n] = acc[i][j][r] + bv;
    }
  }
}

// ---------------- gather + bias + relu + residual (in place on h) ----------------

__global__ __launch_bounds__(256) void k_gather(const float* __restrict__ m,
                                                float* __restrict__ h,
                                                const int* __restrict__ row_start,
                                                const int* __restrict__ csr_src,
                                                const float* __restrict__ csr_norm,
                                                const float* __restrict__ dinv,
                                                const float* __restrict__ bias, int N) {
  int wid = (blockIdx.x * 256 + threadIdx.x) >> 6;
  int lane = threadIdx.x & 63;
  if (wid >= N) return;
  const float2* m2 = (const float2*)m;
  float di = dinv[wid];
  float sl = di * di;
  float2 mv = m2[(size_t)wid * 64 + lane];
  float ax = mv.x * sl, ay = mv.y * sl;
  int e0 = row_start[wid], e1 = row_start[wid + 1];
  for (int e = e0; e < e1; ++e) {
    int s = csr_src[e];
    float nr = csr_norm[e];
    float2 v = m2[(size_t)s * 64 + lane];
    ax = fmaf(v.x, nr, ax);
    ay = fmaf(v.y, nr, ay);
  }
  float2 bb = ((const float2*)bias)[lane];
  float2* h2 = (float2*)h;
  float2 hv = h2[(size_t)wid * 64 + lane];
  float2 r;
  r.x = fmaxf(ax + bb.x, 0.f) + hv.x;
  r.y = fmaxf(ay + bb.y, 0.f) + hv.y;
  h2[(size_t)wid * 64 + lane] = r;
}

// ---------------- output: logits + batch index ----------------

__global__ __launch_bounds__(256) void k_out(const float* __restrict__ h,
                                             const float* __restrict__ Wout,
                                             const float* __restrict__ bout,
                                             const int* __restrict__ tool_idx,
                                             const int* __restrict__ query_idx,
                                             const int* __restrict__ batch_vec,
                                             float* __restrict__ out,
                                             int n_tool, int n_query) {
  int wid = (blockIdx.x * 256 + threadIdx.x) >> 6;
  int lane = threadIdx.x & 63;
  int total = n_tool + n_query;
  if (wid >= total) return;
  int node = (wid < n_tool) ? tool_idx[wid] : query_idx[wid - n_tool];
  float2 w = ((const float2*)Wout)[lane];
  float2 hv = ((const float2*)h)[(size_t)node * 64 + lane];
  float s = hv.x * w.x + hv.y * w.y;
#pragma unroll
  for (int off = 32; off > 0; off >>= 1) s += __shfl_down(s, off);
  if (lane == 0) {
    out[wid] = s + bout[0];
    if (wid < n_tool) out[total + wid] = (float)batch_vec[node];
  }
}

// ---------------- launcher ----------------

extern "C" void kernel_launch(void* const* d_in, const int* in_sizes, int n_in,
                              void* d_out, int out_size, void* d_ws, size_t ws_size,
                              hipStream_t stream) {
  const float* x        = (const float*)d_in[0];
  const int*   edge_src = (const int*)d_in[1];
  const int*   edge_dst = (const int*)d_in[2];
  const int*   batch_vec= (const int*)d_in[3];
  const int*   tool_idx = (const int*)d_in[4];
  const int*   query_idx= (const int*)d_in[5];
  const float* W_align  = (const float*)d_in[6];
  const float* b_align  = (const float*)d_in[7];
  const float* W1       = (const float*)d_in[8];
  const float* b1       = (const float*)d_in[9];
  const float* W2       = (const float*)d_in[10];
  const float* b2       = (const float*)d_in[11];
  const float* W_out    = (const float*)d_in[12];
  const float* b_out    = (const float*)d_in[13];

  const int N   = in_sizes[3];
  const int E   = in_sizes[1];
  const int DIN = in_sizes[0] / N;     // 768
  const int n_tool  = in_sizes[4];
  const int n_query = in_sizes[5];
  (void)n_in; (void)out_size; (void)ws_size;

  char* p = (char*)d_ws;
  auto alloc = [&](size_t bytes) {
    void* r = (void*)p;
    p += (bytes + 255) & ~(size_t)255;
    return r;
  };
  int*   degi      = (int*)alloc((size_t)N * 4);
  float* dinv      = (float*)alloc((size_t)N * 4);
  int*   row_start = (int*)alloc((size_t)(N + 1) * 4);
  int*   fillc     = (int*)alloc((size_t)N * 4);
  int*   csr_src   = (int*)alloc((size_t)E * 4);
  float* csr_norm  = (float*)alloc((size_t)E * 4);
  float* h         = (float*)alloc((size_t)N * HDIM * 4);
  float* m         = (float*)alloc((size_t)N * HDIM * 4);
  int*   bsum      = (int*)alloc((size_t)1024 * 4);
  u16*   WthA      = (u16*)alloc((size_t)DIN * HDIM * 2);   // align weight hi, tiled
  u16*   WtlA      = (u16*)alloc((size_t)DIN * HDIM * 2);
  u16*   Wth1      = (u16*)alloc((size_t)HDIM * HDIM * 2);
  u16*   Wtl1      = (u16*)alloc((size_t)HDIM * HDIM * 2);
  u16*   Wth2      = (u16*)alloc((size_t)HDIM * HDIM * 2);
  u16*   Wtl2      = (u16*)alloc((size_t)HDIM * HDIM * 2);

  hipMemsetAsync(degi, 0, (size_t)N * 4, stream);
  hipMemsetAsync(fillc, 0, (size_t)N * 4, stream);

  const int nblkE = (E + 255) / 256;
  const int nblkN = (N + 255) / 256;   // 391 (<=512 required for scan2)

  // CSR build
  k_count<<<nblkE, 256, 0, stream>>>(edge_dst, degi, E);
  k_dinv<<<nblkN, 256, 0, stream>>>(degi, dinv, N);
  k_scan1<<<nblkN, 256, 0, stream>>>(degi, row_start, bsum, N);
  k_scan2<<<1, 512, 0, stream>>>(bsum, nblkN);
  k_scan3<<<nblkN, 256, 0, stream>>>(row_start, bsum, N, E);
  k_fill<<<nblkE, 256, 0, stream>>>(edge_src, edge_dst, row_start, fillc, dinv,
                                    csr_src, csr_norm, E);

  // weight pre-split (tiled hi/lo bf16)
  k_split_w<<<(DIN * HDIM + 255) / 256, 256, 0, stream>>>(W_align, WthA, WtlA, DIN * HDIM);
  k_split_w<<<(HDIM * HDIM + 255) / 256, 256, 0, stream>>>(W1, Wth1, Wtl1, HDIM * HDIM);
  k_split_w<<<(HDIM * HDIM + 255) / 256, 256, 0, stream>>>(W2, Wth2, Wtl2, HDIM * HDIM);

  const int gemmBlocks = (N + 127) / 128;
  const int waveBlocks = (N * 64 + 255) / 256;

  // h = x @ W_align + b_align
  k_gemm_bf<768, true><<<gemmBlocks, 256, 0, stream>>>(x, WthA, WtlA, b_align, h, N);

  // layer 1
  k_gemm_bf<128, false><<<gemmBlocks, 256, 0, stream>>>(h, Wth1, Wtl1, nullptr, m, N);
  k_gather<<<waveBlocks, 256, 0, stream>>>(m, h, row_start, csr_src, csr_norm,
                                           dinv, b1, N);
  // layer 2
  k_gemm_bf<128, false><<<gemmBlocks, 256, 0, stream>>>(h, Wth2, Wtl2, nullptr, m, N);
  k_gather<<<waveBlocks, 256, 0, stream>>>(m, h, row_start, csr_src, csr_norm,
                                           dinv, b2, N);

  // outputs
  const int outWaves = n_tool + n_query;
  const int outBlocks = (outWaves * 64 + 255) / 256;
  k_out<<<outBlocks, 256, 0, stream>>>(h, W_out, b_out, tool_idx, query_idx,
                                       batch_vec, (float*)d_out, n_tool, n_query);
}

// Round 4
// 438.730 us; speedup vs baseline: 1.6116x; 1.0018x over previous
//
#include <hip/hip_runtime.h>

// QueryAwareGNN: N=100000, E=600000, DIN=768, H=128, G=100.
// Output (flat f32): tool_logits[99000] | query_logits[1000] | tool_batch_index[99000]

#define HDIM 128

typedef short s16x8 __attribute__((ext_vector_type(8)));
typedef unsigned short u16;
typedef unsigned short u16x8 __attribute__((ext_vector_type(8)));
typedef float f32x4 __attribute__((ext_vector_type(4)));

// split f32 into hi/lo bf16 (truncation; lo captures next 8 mantissa bits)
__device__ inline void split2(float f, u16& hi, u16& lo) {
  unsigned u = __builtin_bit_cast(unsigned, f);
  hi = (u16)(u >> 16);
  float fh = __builtin_bit_cast(float, u & 0xFFFF0000u);
  float fl = f - fh;
  lo = (u16)(__builtin_bit_cast(unsigned, fl) >> 16);
}

// ---------------- zero scratch (rocclr fillBuffer is ~180us for 400KB in-graph!) ----

__global__ __launch_bounds__(256) void k_zero2(int* __restrict__ a,
                                               int* __restrict__ b, int n) {
  int g = blockIdx.x * 256 + threadIdx.x;
  if (g < n) { a[g] = 0; b[g] = 0; }
}

// ---------------- CSR build ----------------

__global__ __launch_bounds__(256) void k_count(const int* __restrict__ dst,
                                               int* __restrict__ degi, int E) {
  int g = blockIdx.x * 256 + threadIdx.x;
  if (g < E) atomicAdd(&degi[dst[g]], 1);
}

__global__ __launch_bounds__(256) void k_dinv(const int* __restrict__ degi,
                                              float* __restrict__ dinv, int N) {
  int g = blockIdx.x * 256 + threadIdx.x;
  if (g < N) dinv[g] = rsqrtf((float)(degi[g] + 1));  // +1 self-loop
}

__global__ __launch_bounds__(256) void k_scan1(const int* __restrict__ in,
                                               int* __restrict__ out,
                                               int* __restrict__ bsum, int n) {
  __shared__ int s[256];
  int t = threadIdx.x, g = blockIdx.x * 256 + t;
  int v = (g < n) ? in[g] : 0;
  s[t] = v;
  for (int off = 1; off < 256; off <<= 1) {
    __syncthreads();
    int x = (t >= off) ? s[t - off] : 0;
    __syncthreads();
    s[t] += x;
  }
  if (g < n) out[g] = s[t] - v;
  if (t == 255) bsum[blockIdx.x] = s[255];
}

__global__ __launch_bounds__(512) void k_scan2(int* __restrict__ bsum, int nb) {
  __shared__ int s[512];
  int t = threadIdx.x;
  int v = (t < nb) ? bsum[t] : 0;
  s[t] = v;
  for (int off = 1; off < 512; off <<= 1) {
    __syncthreads();
    int x = (t >= off) ? s[t - off] : 0;
    __syncthreads();
    s[t] += x;
  }
  if (t < nb) bsum[t] = s[t] - v;
}

__global__ __launch_bounds__(256) void k_scan3(int* __restrict__ row_start,
                                               const int* __restrict__ bsum,
                                               int n, int total) {
  int g = blockIdx.x * 256 + threadIdx.x;
  if (g < n) row_start[g] += bsum[g >> 8];
  if (g == 0) row_start[n] = total;
}

__global__ __launch_bounds__(256) void k_fill(const int* __restrict__ src,
                                              const int* __restrict__ dst,
                                              const int* __restrict__ row_start,
                                              int* __restrict__ fill,
                                              const float* __restrict__ dinv,
                                              int* __restrict__ csr_src,
                                              float* __restrict__ csr_norm, int E) {
  int g = blockIdx.x * 256 + threadIdx.x;
  if (g < E) {
    int s = src[g], d = dst[g];
    int p = atomicAdd(&fill[d], 1);
    int o = row_start[d] + p;
    csr_src[o] = s;
    csr_norm[o] = dinv[s] * dinv[d];
  }
}

// ---------------- weight pre-split: W[K][128] -> tiled hi/lo bf16 ----------------
// Tiled layout: th[(k/32)][n][k%32]  (each k-block is the exact 8KB LDS image)

__global__ __launch_bounds__(256) void k_split_w(const float* __restrict__ W,
                                                 u16* __restrict__ th,
                                                 u16* __restrict__ tl, int total) {
  int g = blockIdx.x * 256 + threadIdx.x;
  if (g >= total) return;
  int n = g & 127, k = g >> 7;
  u16 h, l;
  split2(W[g], h, l);
  int o = ((k >> 5) << 12) | (n << 5) | (k & 31);
  th[o] = h;
  tl[o] = l;
}

// ---------------- split-bf16 MFMA GEMM: C[M,128] = A[M,K] @ W[K,128] (+bias) ----
// 128x128 tile, BK=32, 256 threads (4 waves 2x2, each wave 64x64 via 16x16x32).

template <int K, bool BIAS>
__global__ __launch_bounds__(256) void k_gemm_bf(const float* __restrict__ A,
                                                 const u16* __restrict__ Bth,
                                                 const u16* __restrict__ Btl,
                                                 const float* __restrict__ bias,
                                                 float* __restrict__ C, int M) {
  __shared__ u16 Ah[128][40];  // pad to 40 (80B rows, 16B aligned)
  __shared__ u16 Al[128][40];
  __shared__ u16 Bh[128][40];  // B stored transposed: Bh[n][k]
  __shared__ u16 Bl[128][40];

  const int t = threadIdx.x;
  const int m0 = blockIdx.x << 7;
  const int lane = t & 63, w = t >> 6;
  const int wm = (w >> 1) << 6, wn = (w & 1) << 6;
  const int fr = lane & 15;          // row (A) / col (B) within fragment
  const int fk = (lane >> 4) << 3;   // k offset within fragment
  const int srow = t >> 1;           // staging: row 0..127
  const int scol = (t & 1) << 4;     // staging: col 0 or 16

  f32x4 acc[4][4] = {};
  const bool valid = (m0 + srow) < M;
  const float* arow = A + (size_t)(m0 + srow) * K + scol;

  for (int kb = 0; kb < K; kb += 32) {
    // ---- A stage: 16 f32 per thread -> split -> 2x ds_write_b128 per half
    f32x4 v0 = {}, v1 = {}, v2 = {}, v3 = {};
    if (valid) {
      const float* ap = arow + kb;
      v0 = *(const f32x4*)(ap + 0);
      v1 = *(const f32x4*)(ap + 4);
      v2 = *(const f32x4*)(ap + 8);
      v3 = *(const f32x4*)(ap + 12);
    }
    u16x8 h0, h1, l0, l1;
#pragma unroll
    for (int j = 0; j < 4; ++j) {
      u16 hh, ll;
      split2(v0[j], hh, ll); h0[j] = hh; l0[j] = ll;
      split2(v1[j], hh, ll); h0[j + 4] = hh; l0[j + 4] = ll;
      split2(v2[j], hh, ll); h1[j] = hh; l1[j] = ll;
      split2(v3[j], hh, ll); h1[j + 4] = hh; l1[j + 4] = ll;
    }
    *(u16x8*)&Ah[srow][scol] = h0;
    *(u16x8*)&Ah[srow][scol + 8] = h1;
    *(u16x8*)&Al[srow][scol] = l0;
    *(u16x8*)&Al[srow][scol + 8] = l1;

    // ---- B stage: coalesced 32B/thread from pre-tiled weights
    {
      const u16* bsrc = Bth + ((size_t)(kb >> 5) << 12) + (t << 4);
      u16x8 p0 = *(const u16x8*)bsrc;
      u16x8 p1 = *(const u16x8*)(bsrc + 8);
      const u16* bsrc2 = Btl + ((size_t)(kb >> 5) << 12) + (t << 4);
      u16x8 q0 = *(const u16x8*)bsrc2;
      u16x8 q1 = *(const u16x8*)(bsrc2 + 8);
      int bn = t >> 1, bseg = (t & 1) << 4;
      *(u16x8*)&Bh[bn][bseg] = p0;
      *(u16x8*)&Bh[bn][bseg + 8] = p1;
      *(u16x8*)&Bl[bn][bseg] = q0;
      *(u16x8*)&Bl[bn][bseg + 8] = q1;
    }
    __syncthreads();

    // ---- fragments + 48 MFMAs
    s16x8 ah[4], al[4], bh[4], bl[4];
#pragma unroll
    for (int i = 0; i < 4; ++i) {
      ah[i] = *(const s16x8*)&Ah[wm + (i << 4) + fr][fk];
      al[i] = *(const s16x8*)&Al[wm + (i << 4) + fr][fk];
      bh[i] = *(const s16x8*)&Bh[wn + (i << 4) + fr][fk];
      bl[i] = *(const s16x8*)&Bl[wn + (i << 4) + fr][fk];
    }
#pragma unroll
    for (int i = 0; i < 4; ++i)
#pragma unroll
      for (int j = 0; j < 4; ++j) {
        acc[i][j] = __builtin_amdgcn_mfma_f32_16x16x32_bf16(ah[i], bh[j], acc[i][j], 0, 0, 0);
        acc[i][j] = __builtin_amdgcn_mfma_f32_16x16x32_bf16(ah[i], bl[j], acc[i][j], 0, 0, 0);
        acc[i][j] = __builtin_amdgcn_mfma_f32_16x16x32_bf16(al[i], bh[j], acc[i][j], 0, 0, 0);
      }
    __syncthreads();
  }

  // ---- epilogue: C/D layout col=lane&15, row=(lane>>4)*4+reg
  const int cr = (lane >> 4) << 2;
#pragma unroll
  for (int i = 0; i < 4; ++i) {
    int mbase = m0 + wm + (i << 4) + cr;
#pragma unroll
    for (int j = 0; j < 4; ++j) {
      int n = wn + (j << 4) + fr;
      float bv = BIAS ? bias[n] : 0.0f;
#pragma unroll
      for (int r = 0; r < 4; ++r)
        if (mbase + r < M) C[(size_t)(mbase + r) * HDIM + n] = acc[i][j][r] + bv;
    }
  }
}

// ---------------- gather + bias + relu + residual (in place on h) ----------------

__global__ __launch_bounds__(256) void k_gather(const float* __restrict__ m,
                                                float* __restrict__ h,
                                                const int* __restrict__ row_start,
                                                const int* __restrict__ csr_src,
                                                const float* __restrict__ csr_norm,
                                                const float* __restrict__ dinv,
                                                const float* __restrict__ bias, int N) {
  int wid = (blockIdx.x * 256 + threadIdx.x) >> 6;
  int lane = threadIdx.x & 63;
  if (wid >= N) return;
  const float2* m2 = (const float2*)m;
  float di = dinv[wid];
  float sl = di * di;
  float2 mv = m2[(size_t)wid * 64 + lane];
  float ax = mv.x * sl, ay = mv.y * sl;
  int e0 = row_start[wid], e1 = row_start[wid + 1];
  for (int e = e0; e < e1; ++e) {
    int s = csr_src[e];
    float nr = csr_norm[e];
    float2 v = m2[(size_t)s * 64 + lane];
    ax = fmaf(v.x, nr, ax);
    ay = fmaf(v.y, nr, ay);
  }
  float2 bb = ((const float2*)bias)[lane];
  float2* h2 = (float2*)h;
  float2 hv = h2[(size_t)wid * 64 + lane];
  float2 r;
  r.x = fmaxf(ax + bb.x, 0.f) + hv.x;
  r.y = fmaxf(ay + bb.y, 0.f) + hv.y;
  h2[(size_t)wid * 64 + lane] = r;
}

// ---------------- output: logits + batch index ----------------

__global__ __launch_bounds__(256) void k_out(const float* __restrict__ h,
                                             const float* __restrict__ Wout,
                                             const float* __restrict__ bout,
                                             const int* __restrict__ tool_idx,
                                             const int* __restrict__ query_idx,
                                             const int* __restrict__ batch_vec,
                                             float* __restrict__ out,
                                             int n_tool, int n_query) {
  int wid = (blockIdx.x * 256 + threadIdx.x) >> 6;
  int lane = threadIdx.x & 63;
  int total = n_tool + n_query;
  if (wid >= total) return;
  int node = (wid < n_tool) ? tool_idx[wid] : query_idx[wid - n_tool];
  float2 w = ((const float2*)Wout)[lane];
  float2 hv = ((const float2*)h)[(size_t)node * 64 + lane];
  float s = hv.x * w.x + hv.y * w.y;
#pragma unroll
  for (int off = 32; off > 0; off >>= 1) s += __shfl_down(s, off);
  if (lane == 0) {
    out[wid] = s + bout[0];
    if (wid < n_tool) out[total + wid] = (float)batch_vec[node];
  }
}

// ---------------- launcher ----------------

extern "C" void kernel_launch(void* const* d_in, const int* in_sizes, int n_in,
                              void* d_out, int out_size, void* d_ws, size_t ws_size,
                              hipStream_t stream) {
  const float* x        = (const float*)d_in[0];
  const int*   edge_src = (const int*)d_in[1];
  const int*   edge_dst = (const int*)d_in[2];
  const int*   batch_vec= (const int*)d_in[3];
  const int*   tool_idx = (const int*)d_in[4];
  const int*   query_idx= (const int*)d_in[5];
  const float* W_align  = (const float*)d_in[6];
  const float* b_align  = (const float*)d_in[7];
  const float* W1       = (const float*)d_in[8];
  const float* b1       = (const float*)d_in[9];
  const float* W2       = (const float*)d_in[10];
  const float* b2       = (const float*)d_in[11];
  const float* W_out    = (const float*)d_in[12];
  const float* b_out    = (const float*)d_in[13];

  const int N   = in_sizes[3];
  const int E   = in_sizes[1];
  const int DIN = in_sizes[0] / N;     // 768
  const int n_tool  = in_sizes[4];
  const int n_query = in_sizes[5];
  (void)n_in; (void)out_size; (void)ws_size;

  char* p = (char*)d_ws;
  auto alloc = [&](size_t bytes) {
    void* r = (void*)p;
    p += (bytes + 255) & ~(size_t)255;
    return r;
  };
  int*   degi      = (int*)alloc((size_t)N * 4);
  float* dinv      = (float*)alloc((size_t)N * 4);
  int*   row_start = (int*)alloc((size_t)(N + 1) * 4);
  int*   fillc     = (int*)alloc((size_t)N * 4);
  int*   csr_src   = (int*)alloc((size_t)E * 4);
  float* csr_norm  = (float*)alloc((size_t)E * 4);
  float* h         = (float*)alloc((size_t)N * HDIM * 4);
  float* m         = (float*)alloc((size_t)N * HDIM * 4);
  int*   bsum      = (int*)alloc((size_t)1024 * 4);
  u16*   WthA      = (u16*)alloc((size_t)DIN * HDIM * 2);   // align weight hi, tiled
  u16*   WtlA      = (u16*)alloc((size_t)DIN * HDIM * 2);
  u16*   Wth1      = (u16*)alloc((size_t)HDIM * HDIM * 2);
  u16*   Wtl1      = (u16*)alloc((size_t)HDIM * HDIM * 2);
  u16*   Wth2      = (u16*)alloc((size_t)HDIM * HDIM * 2);
  u16*   Wtl2      = (u16*)alloc((size_t)HDIM * HDIM * 2);

  const int nblkE = (E + 255) / 256;
  const int nblkN = (N + 255) / 256;   // 391 (<=512 required for scan2)

  // zero degi+fillc with our own kernel (rocclr fillBuffer was 181us/400KB in-graph)
  k_zero2<<<nblkN, 256, 0, stream>>>(degi, fillc, N);

  // CSR build
  k_count<<<nblkE, 256, 0, stream>>>(edge_dst, degi, E);
  k_dinv<<<nblkN, 256, 0, stream>>>(degi, dinv, N);
  k_scan1<<<nblkN, 256, 0, stream>>>(degi, row_start, bsum, N);
  k_scan2<<<1, 512, 0, stream>>>(bsum, nblkN);
  k_scan3<<<nblkN, 256, 0, stream>>>(row_start, bsum, N, E);
  k_fill<<<nblkE, 256, 0, stream>>>(edge_src, edge_dst, row_start, fillc, dinv,
                                    csr_src, csr_norm, E);

  // weight pre-split (tiled hi/lo bf16)
  k_split_w<<<(DIN * HDIM + 255) / 256, 256, 0, stream>>>(W_align, WthA, WtlA, DIN * HDIM);
  k_split_w<<<(HDIM * HDIM + 255) / 256, 256, 0, stream>>>(W1, Wth1, Wtl1, HDIM * HDIM);
  k_split_w<<<(HDIM * HDIM + 255) / 256, 256, 0, stream>>>(W2, Wth2, Wtl2, HDIM * HDIM);

  const int gemmBlocks = (N + 127) / 128;
  const int waveBlocks = (N * 64 + 255) / 256;

  // h = x @ W_align + b_align
  k_gemm_bf<768, true><<<gemmBlocks, 256, 0, stream>>>(x, WthA, WtlA, b_align, h, N);

  // layer 1
  k_gemm_bf<128, false><<<gemmBlocks, 256, 0, stream>>>(h, Wth1, Wtl1, nullptr, m, N);
  k_gather<<<waveBlocks, 256, 0, stream>>>(m, h, row_start, csr_src, csr_norm,
                                           dinv, b1, N);
  // layer 2
  k_gemm_bf<128, false><<<gemmBlocks, 256, 0, stream>>>(h, Wth2, Wtl2, nullptr, m, N);
  k_gather<<<waveBlocks, 256, 0, stream>>>(m, h, row_start, csr_src, csr_norm,
                                           dinv, b2, N);

  // outputs
  const int outWaves = n_tool + n_query;
  const int outBlocks = (outWaves * 64 + 255) / 256;
  k_out<<<outBlocks, 256, 0, stream>>>(h, W_out, b_out, tool_idx, query_idx,
                                       batch_vec, (float*)d_out, n_tool, n_query);
}

// Round 6
// 425.846 us; speedup vs baseline: 1.6604x; 1.0303x over previous
//
#include <hip/hip_runtime.h>

// QueryAwareGNN: N=100000, E=600000, DIN=768, H=128, G=100.
// Output (flat f32): tool_logits[99000] | query_logits[1000] | tool_batch_index[99000]

#define HDIM 128

typedef short s16x8 __attribute__((ext_vector_type(8)));
typedef unsigned short u16;
typedef unsigned short u16x8 __attribute__((ext_vector_type(8)));
typedef float f32x4 __attribute__((ext_vector_type(4)));

// split f32 into hi/lo bf16 (truncation hi; lo captures next 8 mantissa bits)
__device__ inline void split2(float f, u16& hi, u16& lo) {
  unsigned u = __builtin_bit_cast(unsigned, f);
  hi = (u16)(u >> 16);
  float fh = __builtin_bit_cast(float, u & 0xFFFF0000u);
  float fl = f - fh;
  lo = (u16)(__builtin_bit_cast(unsigned, fl) >> 16);
}

// round-to-nearest-even f32 -> bf16
__device__ inline u16 bf16rne(float f) {
  unsigned u = __builtin_bit_cast(unsigned, f);
  u += 0x7FFFu + ((u >> 16) & 1u);
  return (u16)(u >> 16);
}

// ---------------- zero scratch (rocclr fillBuffer is ~180us for 400KB in-graph!) ----

__global__ __launch_bounds__(256) void k_zero(int* __restrict__ a, int n) {
  int g = blockIdx.x * 256 + threadIdx.x;
  if (g < n) a[g] = 0;
}

// ---------------- CSR build ----------------

__global__ __launch_bounds__(256) void k_count(const int* __restrict__ dst,
                                               int* __restrict__ degi, int E) {
  int g = blockIdx.x * 256 + threadIdx.x;
  if (g < E) atomicAdd(&degi[dst[g]], 1);
}

// scan1 fused with dinv computation and fillc zeroing
__global__ __launch_bounds__(256) void k_scan1(const int* __restrict__ in,
                                               int* __restrict__ out,
                                               int* __restrict__ bsum,
                                               float* __restrict__ dinv,
                                               int* __restrict__ fillc, int n) {
  __shared__ int s[256];
  int t = threadIdx.x, g = blockIdx.x * 256 + t;
  int v = (g < n) ? in[g] : 0;
  if (g < n) {
    dinv[g] = rsqrtf((float)(v + 1));  // +1 self-loop
    fillc[g] = 0;
  }
  s[t] = v;
  for (int off = 1; off < 256; off <<= 1) {
    __syncthreads();
    int x = (t >= off) ? s[t - off] : 0;
    __syncthreads();
    s[t] += x;
  }
  if (g < n) out[g] = s[t] - v;
  if (t == 255) bsum[blockIdx.x] = s[255];
}

__global__ __launch_bounds__(512) void k_scan2(int* __restrict__ bsum, int nb) {
  __shared__ int s[512];
  int t = threadIdx.x;
  int v = (t < nb) ? bsum[t] : 0;
  s[t] = v;
  for (int off = 1; off < 512; off <<= 1) {
    __syncthreads();
    int x = (t >= off) ? s[t - off] : 0;
    __syncthreads();
    s[t] += x;
  }
  if (t < nb) bsum[t] = s[t] - v;
}

__global__ __launch_bounds__(256) void k_scan3(int* __restrict__ row_start,
                                               const int* __restrict__ bsum,
                                               int n, int total) {
  int g = blockIdx.x * 256 + threadIdx.x;
  if (g < n) row_start[g] += bsum[g >> 8];
  if (g == 0) row_start[n] = total;
}

__global__ __launch_bounds__(256) void k_fill(const int* __restrict__ src,
                                              const int* __restrict__ dst,
                                              const int* __restrict__ row_start,
                                              int* __restrict__ fill,
                                              const float* __restrict__ dinv,
                                              int* __restrict__ csr_src,
                                              float* __restrict__ csr_norm, int E) {
  int g = blockIdx.x * 256 + threadIdx.x;
  if (g < E) {
    int s = src[g], d = dst[g];
    int p = atomicAdd(&fill[d], 1);
    int o = row_start[d] + p;
    csr_src[o] = s;
    csr_norm[o] = dinv[s] * dinv[d];
  }
}

// ---------------- weight pre-split: all three W -> tiled hi/lo bf16 ----------------
// Tiled layout: th[(k/32)][n][k%32]  (each k-block is the exact 8KB LDS image)

__global__ __launch_bounds__(256) void k_split3(const float* __restrict__ Wa,
                                                const float* __restrict__ W1,
                                                const float* __restrict__ W2,
                                                u16* __restrict__ tha, u16* __restrict__ tla,
                                                u16* __restrict__ th1, u16* __restrict__ tl1,
                                                u16* __restrict__ th2, u16* __restrict__ tl2,
                                                int na, int n1) {
  int g = blockIdx.x * 256 + threadIdx.x;
  const float* W;
  u16 *th, *tl;
  int idx;
  if (g < na) { W = Wa; th = tha; tl = tla; idx = g; }
  else if (g < na + n1) { W = W1; th = th1; tl = tl1; idx = g - na; }
  else if (g < na + 2 * n1) { W = W2; th = th2; tl = tl2; idx = g - na - n1; }
  else return;
  int n = idx & 127, k = idx >> 7;
  u16 h, l;
  split2(W[idx], h, l);
  int o = ((k >> 5) << 12) | (n << 5) | (k & 31);
  th[o] = h;
  tl[o] = l;
}

// ---------------- MFMA GEMM: C[M,128] = A[M,K] @ W[K,128] (+bias) ----------------
// A rounded to bf16 (RNE); B split hi+lo -> C = A*(Bh+Bl): 2 MFMAs per fragment.
// 128x128 tile, BK=32, 256 threads (4 waves 2x2, each wave 64x64 via 16x16x32).

template <int K, bool BIAS>
__global__ __launch_bounds__(256) void k_gemm_bf(const float* __restrict__ A,
                                                 const u16* __restrict__ Bth,
                                                 const u16* __restrict__ Btl,
                                                 const float* __restrict__ bias,
                                                 float* __restrict__ C, int M) {
  __shared__ u16 Ah[128][40];  // pad to 40 (80B rows; b128 frag reads at min aliasing)
  __shared__ u16 Bh[128][40];  // B stored transposed: Bh[n][k]
  __shared__ u16 Bl[128][40];

  const int t = threadIdx.x;
  const int m0 = blockIdx.x << 7;
  const int lane = t & 63, w = t >> 6;
  const int wm = (w >> 1) << 6, wn = (w & 1) << 6;
  const int fr = lane & 15;          // row (A) / col (B) within fragment
  const int fk = (lane >> 4) << 3;   // k offset within fragment
  const int srow = t >> 1;           // staging: row 0..127
  const int scol = (t & 1) << 4;     // staging: col 0 or 16

  f32x4 acc[4][4] = {};
  const bool valid = (m0 + srow) < M;
  const float* arow = A + (size_t)(m0 + srow) * K + scol;

  for (int kb = 0; kb < K; kb += 32) {
    // ---- A stage: 16 f32 per thread -> bf16 RNE -> 2x ds_write_b128
    f32x4 v0 = {}, v1 = {}, v2 = {}, v3 = {};
    if (valid) {
      const float* ap = arow + kb;
      v0 = *(const f32x4*)(ap + 0);
      v1 = *(const f32x4*)(ap + 4);
      v2 = *(const f32x4*)(ap + 8);
      v3 = *(const f32x4*)(ap + 12);
    }
    u16x8 h0, h1;
#pragma unroll
    for (int j = 0; j < 4; ++j) {
      h0[j] = bf16rne(v0[j]);
      h0[j + 4] = bf16rne(v1[j]);
      h1[j] = bf16rne(v2[j]);
      h1[j + 4] = bf16rne(v3[j]);
    }
    *(u16x8*)&Ah[srow][scol] = h0;
    *(u16x8*)&Ah[srow][scol + 8] = h1;

    // ---- B stage: coalesced 32B/thread from pre-tiled weights
    {
      const u16* bsrc = Bth + ((size_t)(kb >> 5) << 12) + (t << 4);
      u16x8 p0 = *(const u16x8*)bsrc;
      u16x8 p1 = *(const u16x8*)(bsrc + 8);
      const u16* bsrc2 = Btl + ((size_t)(kb >> 5) << 12) + (t << 4);
      u16x8 q0 = *(const u16x8*)bsrc2;
      u16x8 q1 = *(const u16x8*)(bsrc2 + 8);
      int bn = t >> 1, bseg = (t & 1) << 4;
      *(u16x8*)&Bh[bn][bseg] = p0;
      *(u16x8*)&Bh[bn][bseg + 8] = p1;
      *(u16x8*)&Bl[bn][bseg] = q0;
      *(u16x8*)&Bl[bn][bseg + 8] = q1;
    }
    __syncthreads();

    // ---- fragments + 32 MFMAs
    s16x8 ah[4], bh[4], bl[4];
#pragma unroll
    for (int i = 0; i < 4; ++i) {
      ah[i] = *(const s16x8*)&Ah[wm + (i << 4) + fr][fk];
      bh[i] = *(const s16x8*)&Bh[wn + (i << 4) + fr][fk];
      bl[i] = *(const s16x8*)&Bl[wn + (i << 4) + fr][fk];
    }
#pragma unroll
    for (int i = 0; i < 4; ++i)
#pragma unroll
      for (int j = 0; j < 4; ++j) {
        acc[i][j] = __builtin_amdgcn_mfma_f32_16x16x32_bf16(ah[i], bh[j], acc[i][j], 0, 0, 0);
        acc[i][j] = __builtin_amdgcn_mfma_f32_16x16x32_bf16(ah[i], bl[j], acc[i][j], 0, 0, 0);
      }
    __syncthreads();
  }

  // ---- epilogue: C/D layout col=lane&15, row=(lane>>4)*4+reg
  const int cr = (lane >> 4) << 2;
#pragma unroll
  for (int i = 0; i < 4; ++i) {
    int mbase = m0 + wm + (i << 4) + cr;
#pragma unroll
    for (int j = 0; j < 4; ++j) {
      int n = wn + (j << 4) + fr;
      float bv = BIAS ? bias[n] : 0.0f;
#pragma unroll
      for (int r = 0; r < 4; ++r)
        if (mbase + r < M) C[(size_t)(mbase + r) * HDIM + n] = acc[i][j][r] + bv;
    }
  }
}

// ---------------- gather + bias + relu + residual (in place on h) ----------------

__global__ __launch_bounds__(256) void k_gather(const float* __restrict__ m,
                                                float* __restrict__ h,
                                                const int* __restrict__ row_start,
                                                const int* __restrict__ csr_src,
                                                const float* __restrict__ csr_norm,
                                                const float* __restrict__ dinv,
                                                const float* __restrict__ bias, int N) {
  int wid = (blockIdx.x * 256 + threadIdx.x) >> 6;
  int lane = threadIdx.x & 63;
  if (wid >= N) return;
  const float2* m2 = (const float2*)m;
  float di = dinv[wid];
  float sl = di * di;
  float2 mv = m2[(size_t)wid * 64 + lane];
  float ax = mv.x * sl, ay = mv.y * sl;
  int e0 = row_start[wid], e1 = row_start[wid + 1];
  for (int e = e0; e < e1; ++e) {
    int s = csr_src[e];
    float nr = csr_norm[e];
    float2 v = m2[(size_t)s * 64 + lane];
    ax = fmaf(v.x, nr, ax);
    ay = fmaf(v.y, nr, ay);
  }
  float2 bb = ((const float2*)bias)[lane];
  float2* h2 = (float2*)h;
  float2 hv = h2[(size_t)wid * 64 + lane];
  float2 r;
  r.x = fmaxf(ax + bb.x, 0.f) + hv.x;
  r.y = fmaxf(ay + bb.y, 0.f) + hv.y;
  h2[(size_t)wid * 64 + lane] = r;
}

// ---------------- output: logits + batch index ----------------

__global__ __launch_bounds__(256) void k_out(const float* __restrict__ h,
                                             const float* __restrict__ Wout,
                                             const float* __restrict__ bout,
                                             const int* __restrict__ tool_idx,
                                             const int* __restrict__ query_idx,
                                             const int* __restrict__ batch_vec,
                                             float* __restrict__ out,
                                             int n_tool, int n_query) {
  int wid = (blockIdx.x * 256 + threadIdx.x) >> 6;
  int lane = threadIdx.x & 63;
  int total = n_tool + n_query;
  if (wid >= total) return;
  int node = (wid < n_tool) ? tool_idx[wid] : query_idx[wid - n_tool];
  float2 w = ((const float2*)Wout)[lane];
  float2 hv = ((const float2*)h)[(size_t)node * 64 + lane];
  float s = hv.x * w.x + hv.y * w.y;
#pragma unroll
  for (int off = 32; off > 0; off >>= 1) s += __shfl_down(s, off);
  if (lane == 0) {
    out[wid] = s + bout[0];
    if (wid < n_tool) out[total + wid] = (float)batch_vec[node];
  }
}

// ---------------- launcher ----------------

extern "C" void kernel_launch(void* const* d_in, const int* in_sizes, int n_in,
                              void* d_out, int out_size, void* d_ws, size_t ws_size,
                              hipStream_t stream) {
  const float* x        = (const float*)d_in[0];
  const int*   edge_src = (const int*)d_in[1];
  const int*   edge_dst = (const int*)d_in[2];
  const int*   batch_vec= (const int*)d_in[3];
  const int*   tool_idx = (const int*)d_in[4];
  const int*   query_idx= (const int*)d_in[5];
  const float* W_align  = (const float*)d_in[6];
  const float* b_align  = (const float*)d_in[7];
  const float* W1       = (const float*)d_in[8];
  const float* b1       = (const float*)d_in[9];
  const float* W2       = (const float*)d_in[10];
  const float* b2       = (const float*)d_in[11];
  const float* W_out    = (const float*)d_in[12];
  const float* b_out    = (const float*)d_in[13];

  const int N   = in_sizes[3];
  const int E   = in_sizes[1];
  const int DIN = in_sizes[0] / N;     // 768
  const int n_tool  = in_sizes[4];
  const int n_query = in_sizes[5];
  (void)n_in; (void)out_size; (void)ws_size;

  char* p = (char*)d_ws;
  auto alloc = [&](size_t bytes) {
    void* r = (void*)p;
    p += (bytes + 255) & ~(size_t)255;
    return r;
  };
  int*   degi      = (int*)alloc((size_t)N * 4);
  float* dinv      = (float*)alloc((size_t)N * 4);
  int*   row_start = (int*)alloc((size_t)(N + 1) * 4);
  int*   fillc     = (int*)alloc((size_t)N * 4);
  int*   csr_src   = (int*)alloc((size_t)E * 4);
  float* csr_norm  = (float*)alloc((size_t)E * 4);
  float* h         = (float*)alloc((size_t)N * HDIM * 4);
  float* m         = (float*)alloc((size_t)N * HDIM * 4);
  int*   bsum      = (int*)alloc((size_t)1024 * 4);
  u16*   WthA      = (u16*)alloc((size_t)DIN * HDIM * 2);   // align weight hi, tiled
  u16*   WtlA      = (u16*)alloc((size_t)DIN * HDIM * 2);
  u16*   Wth1      = (u16*)alloc((size_t)HDIM * HDIM * 2);
  u16*   Wtl1      = (u16*)alloc((size_t)HDIM * HDIM * 2);
  u16*   Wth2      = (u16*)alloc((size_t)HDIM * HDIM * 2);
  u16*   Wtl2      = (u16*)alloc((size_t)HDIM * HDIM * 2);

  const int nblkE = (E + 255) / 256;
  const int nblkN = (N + 255) / 256;   // 391 (<=512 required for scan2)

  // CSR build (degi zeroed by our kernel; fillc zeroed inside scan1)
  k_zero<<<nblkN, 256, 0, stream>>>(degi, N);
  k_count<<<nblkE, 256, 0, stream>>>(edge_dst, degi, E);
  k_scan1<<<nblkN, 256, 0, stream>>>(degi, row_start, bsum, dinv, fillc, N);
  k_scan2<<<1, 512, 0, stream>>>(bsum, nblkN);
  k_scan3<<<nblkN, 256, 0, stream>>>(row_start, bsum, N, E);
  k_fill<<<nblkE, 256, 0, stream>>>(edge_src, edge_dst, row_start, fillc, dinv,
                                    csr_src, csr_norm, E);

  // weight pre-split (tiled hi/lo bf16), one launch for all three
  const int na = DIN * HDIM, n1 = HDIM * HDIM;
  k_split3<<<(na + 2 * n1 + 255) / 256, 256, 0, stream>>>(
      W_align, W1, W2, WthA, WtlA, Wth1, Wtl1, Wth2, Wtl2, na, n1);

  const int gemmBlocks = (N + 127) / 128;
  const int waveBlocks = (N * 64 + 255) / 256;

  // h = x @ W_align + b_align
  k_gemm_bf<768, true><<<gemmBlocks, 256, 0, stream>>>(x, WthA, WtlA, b_align, h, N);

  // layer 1
  k_gemm_bf<128, false><<<gemmBlocks, 256, 0, stream>>>(h, Wth1, Wtl1, nullptr, m, N);
  k_gather<<<waveBlocks, 256, 0, stream>>>(m, h, row_start, csr_src, csr_norm,
                                           dinv, b1, N);
  // layer 2
  k_gemm_bf<128, false><<<gemmBlocks, 256, 0, stream>>>(h, Wth2, Wtl2, nullptr, m, N);
  k_gather<<<waveBlocks, 256, 0, stream>>>(m, h, row_start, csr_src, csr_norm,
                                           dinv, b2, N);

  // outputs
  const int outWaves = n_tool + n_query;
  const int outBlocks = (outWaves * 64 + 255) / 256;
  k_out<<<outBlocks, 256, 0, stream>>>(h, W_out, b_out, tool_idx, query_idx,
                                       batch_vec, (float*)d_out, n_tool, n_query);
}

// Round 8
// 366.938 us; speedup vs baseline: 1.9269x; 1.1605x over previous
//
#include <hip/hip_runtime.h>

// QueryAwareGNN: N=100000, E=600000, DIN=768, H=128, G=100.
// Output (flat f32): tool_logits[99000] | query_logits[1000] | tool_batch_index[99000]

#define HDIM 128

typedef short s16x8 __attribute__((ext_vector_type(8)));
typedef unsigned short u16;
typedef unsigned short u16x8 __attribute__((ext_vector_type(8)));
typedef float f32x4 __attribute__((ext_vector_type(4)));

// split f32 into hi/lo bf16 (truncation hi; lo captures next 8 mantissa bits)
__device__ inline void split2(float f, u16& hi, u16& lo) {
  unsigned u = __builtin_bit_cast(unsigned, f);
  hi = (u16)(u >> 16);
  float fh = __builtin_bit_cast(float, u & 0xFFFF0000u);
  float fl = f - fh;
  lo = (u16)(__builtin_bit_cast(unsigned, fl) >> 16);
}

// round-to-nearest-even f32 -> bf16
__device__ inline u16 bf16rne(float f) {
  unsigned u = __builtin_bit_cast(unsigned, f);
  u += 0x7FFFu + ((u >> 16) & 1u);
  return (u16)(u >> 16);
}

// ---------------- zero scratch ----------------

__global__ __launch_bounds__(256) void k_zero(int* __restrict__ a, int n) {
  int g = blockIdx.x * 256 + threadIdx.x;
  if (g < n) a[g] = 0;
}

// ---------------- CSR build ----------------

__global__ __launch_bounds__(256) void k_count(const int* __restrict__ dst,
                                               int* __restrict__ degi, int E) {
  int g = blockIdx.x * 256 + threadIdx.x;
  if (g < E) atomicAdd(&degi[dst[g]], 1);
}

// scan1 fused with dinv computation and fillc zeroing
__global__ __launch_bounds__(256) void k_scan1(const int* __restrict__ in,
                                               int* __restrict__ out,
                                               int* __restrict__ bsum,
                                               float* __restrict__ dinv,
                                               int* __restrict__ fillc, int n) {
  __shared__ int s[256];
  int t = threadIdx.x, g = blockIdx.x * 256 + t;
  int v = (g < n) ? in[g] : 0;
  if (g < n) {
    dinv[g] = rsqrtf((float)(v + 1));  // +1 self-loop
    fillc[g] = 0;
  }
  s[t] = v;
  for (int off = 1; off < 256; off <<= 1) {
    __syncthreads();
    int x = (t >= off) ? s[t - off] : 0;
    __syncthreads();
    s[t] += x;
  }
  if (g < n) out[g] = s[t] - v;
  if (t == 255) bsum[blockIdx.x] = s[255];
}

__global__ __launch_bounds__(512) void k_scan2(int* __restrict__ bsum, int nb) {
  __shared__ int s[512];
  int t = threadIdx.x;
  int v = (t < nb) ? bsum[t] : 0;
  s[t] = v;
  for (int off = 1; off < 512; off <<= 1) {
    __syncthreads();
    int x = (t >= off) ? s[t - off] : 0;
    __syncthreads();
    s[t] += x;
  }
  if (t < nb) bsum[t] = s[t] - v;
}

__global__ __launch_bounds__(256) void k_scan3(int* __restrict__ row_start,
                                               const int* __restrict__ bsum,
                                               int n, int total) {
  int g = blockIdx.x * 256 + threadIdx.x;
  if (g < n) row_start[g] += bsum[g >> 8];
  if (g == 0) row_start[n] = total;
}

__global__ __launch_bounds__(256) void k_fill(const int* __restrict__ src,
                                              const int* __restrict__ dst,
                                              const int* __restrict__ row_start,
                                              int* __restrict__ fill,
                                              const float* __restrict__ dinv,
                                              int* __restrict__ csr_src,
                                              float* __restrict__ csr_norm, int E) {
  int g = blockIdx.x * 256 + threadIdx.x;
  if (g < E) {
    int s = src[g], d = dst[g];
    int p = atomicAdd(&fill[d], 1);
    int o = row_start[d] + p;
    csr_src[o] = s;
    csr_norm[o] = dinv[s] * dinv[d];
  }
}

// ---------------- node -> output slot map, + batch indices ----------------
// pos[node] = output index for its logit. Also writes tool_batch_index part.

__global__ __launch_bounds__(256) void k_posmap(const int* __restrict__ tool_idx,
                                                const int* __restrict__ query_idx,
                                                const int* __restrict__ batch_vec,
                                                int* __restrict__ pos,
                                                float* __restrict__ out,
                                                int n_tool, int n_query) {
  int g = blockIdx.x * 256 + threadIdx.x;
  if (g < n_tool) {
    int nd = tool_idx[g];
    pos[nd] = g;
    out[n_tool + n_query + g] = (float)batch_vec[nd];
  } else if (g < n_tool + n_query) {
    int q = g - n_tool;
    int nd = query_idx[q];
    pos[nd] = n_tool + q;
  }
}

// ---------------- weight pre-split: all three W -> tiled hi/lo bf16 ----------------
// Tiled layout: th[(k/32)][n][k%32]  (each k-block is the exact 8KB LDS image)

__global__ __launch_bounds__(256) void k_split3(const float* __restrict__ Wa,
                                                const float* __restrict__ W1,
                                                const float* __restrict__ W2,
                                                u16* __restrict__ tha, u16* __restrict__ tla,
                                                u16* __restrict__ th1, u16* __restrict__ tl1,
                                                u16* __restrict__ th2, u16* __restrict__ tl2,
                                                int na, int n1) {
  int g = blockIdx.x * 256 + threadIdx.x;
  const float* W;
  u16 *th, *tl;
  int idx;
  if (g < na) { W = Wa; th = tha; tl = tla; idx = g; }
  else if (g < na + n1) { W = W1; th = th1; tl = tl1; idx = g - na; }
  else if (g < na + 2 * n1) { W = W2; th = th2; tl = tl2; idx = g - na - n1; }
  else return;
  int n = idx & 127, k = idx >> 7;
  u16 h, l;
  split2(W[idx], h, l);
  int o = ((k >> 5) << 12) | (n << 5) | (k & 31);
  th[o] = h;
  tl[o] = l;
}

// ---------------- MFMA GEMM: C[M,128] = A[M,K] @ W[K,128] (+bias) ----------------
// A rounded to bf16 (RNE); B split hi+lo -> C = A*(Bh+Bl): 2 MFMAs per fragment.
// 128x128 tile, BK=32, 256 threads (4 waves 2x2, each wave 64x64 via 16x16x32).
// Next-iter A f32 loads issue right after the first barrier (reg prefetch).

template <int K, bool BIAS>
__global__ __launch_bounds__(256) void k_gemm_bf(const float* __restrict__ A,
                                                 const u16* __restrict__ Bth,
                                                 const u16* __restrict__ Btl,
                                                 const float* __restrict__ bias,
                                                 float* __restrict__ C, int M) {
  __shared__ u16 Ah[128][40];  // pad to 40 (80B rows; b128 frag reads at min aliasing)
  __shared__ u16 Bh[128][40];  // B stored transposed: Bh[n][k]
  __shared__ u16 Bl[128][40];

  const int t = threadIdx.x;
  const int m0 = blockIdx.x << 7;
  const int lane = t & 63, w = t >> 6;
  const int wm = (w >> 1) << 6, wn = (w & 1) << 6;
  const int fr = lane & 15;          // row (A) / col (B) within fragment
  const int fk = (lane >> 4) << 3;   // k offset within fragment
  const int srow = t >> 1;           // staging: row 0..127
  const int scol = (t & 1) << 4;     // staging: col 0 or 16

  f32x4 acc[4][4] = {};
  const bool valid = (m0 + srow) < M;
  const float* arow = A + (size_t)(m0 + srow) * K + scol;

  f32x4 v0 = {}, v1 = {}, v2 = {}, v3 = {};
  if (valid) {
    v0 = *(const f32x4*)(arow + 0);
    v1 = *(const f32x4*)(arow + 4);
    v2 = *(const f32x4*)(arow + 8);
    v3 = *(const f32x4*)(arow + 12);
  }

  for (int kb = 0; kb < K; kb += 32) {
    // ---- A stage: current regs -> bf16 RNE -> 2x ds_write_b128
    u16x8 h0, h1;
#pragma unroll
    for (int j = 0; j < 4; ++j) {
      h0[j] = bf16rne(v0[j]);
      h0[j + 4] = bf16rne(v1[j]);
      h1[j] = bf16rne(v2[j]);
      h1[j + 4] = bf16rne(v3[j]);
    }
    *(u16x8*)&Ah[srow][scol] = h0;
    *(u16x8*)&Ah[srow][scol + 8] = h1;

    // ---- B stage: coalesced 32B/thread from pre-tiled weights
    {
      const u16* bsrc = Bth + ((size_t)(kb >> 5) << 12) + (t << 4);
      u16x8 p0 = *(const u16x8*)bsrc;
      u16x8 p1 = *(const u16x8*)(bsrc + 8);
      const u16* bsrc2 = Btl + ((size_t)(kb >> 5) << 12) + (t << 4);
      u16x8 q0 = *(const u16x8*)bsrc2;
      u16x8 q1 = *(const u16x8*)(bsrc2 + 8);
      int bn = t >> 1, bseg = (t & 1) << 4;
      *(u16x8*)&Bh[bn][bseg] = p0;
      *(u16x8*)&Bh[bn][bseg + 8] = p1;
      *(u16x8*)&Bl[bn][bseg] = q0;
      *(u16x8*)&Bl[bn][bseg + 8] = q1;
    }
    __syncthreads();

    // ---- prefetch next A tile into regs (latency hides under MFMA)
    if (valid && kb + 32 < K) {
      const float* ap = arow + kb + 32;
      v0 = *(const f32x4*)(ap + 0);
      v1 = *(const f32x4*)(ap + 4);
      v2 = *(const f32x4*)(ap + 8);
      v3 = *(const f32x4*)(ap + 12);
    }

    // ---- fragments + 32 MFMAs
    s16x8 ah[4], bh[4], bl[4];
#pragma unroll
    for (int i = 0; i < 4; ++i) {
      ah[i] = *(const s16x8*)&Ah[wm + (i << 4) + fr][fk];
      bh[i] = *(const s16x8*)&Bh[wn + (i << 4) + fr][fk];
      bl[i] = *(const s16x8*)&Bl[wn + (i << 4) + fr][fk];
    }
#pragma unroll
    for (int i = 0; i < 4; ++i)
#pragma unroll
      for (int j = 0; j < 4; ++j) {
        acc[i][j] = __builtin_amdgcn_mfma_f32_16x16x32_bf16(ah[i], bh[j], acc[i][j], 0, 0, 0);
        acc[i][j] = __builtin_amdgcn_mfma_f32_16x16x32_bf16(ah[i], bl[j], acc[i][j], 0, 0, 0);
      }
    __syncthreads();
  }

  // ---- epilogue: C/D layout col=lane&15, row=(lane>>4)*4+reg
  const int cr = (lane >> 4) << 2;
#pragma unroll
  for (int i = 0; i < 4; ++i) {
    int mbase = m0 + wm + (i << 4) + cr;
#pragma unroll
    for (int j = 0; j < 4; ++j) {
      int n = wn + (j << 4) + fr;
      float bv = BIAS ? bias[n] : 0.0f;
#pragma unroll
      for (int r = 0; r < 4; ++r)
        if (mbase + r < M) C[(size_t)(mbase + r) * HDIM + n] = acc[i][j][r] + bv;
    }
  }
}

// ---------------- gather + bias + relu + residual ----------------
// One wave per node. Edge indices/norms loaded 64-at-a-time (coalesced) and
// broadcast via shfl -> m-row gathers are independent back-to-back loads.
// FINAL=true: fuse the output projection (dot W_out, shuffle-reduce, scatter
// to out[pos[node]]) and skip the h write entirely.

template <bool FINAL>
__global__ __launch_bounds__(256) void k_gather(const float* __restrict__ m,
                                                float* __restrict__ h,
                                                const int* __restrict__ row_start,
                                                const int* __restrict__ csr_src,
                                                const float* __restrict__ csr_norm,
                                                const float* __restrict__ dinv,
                                                const float* __restrict__ bias,
                                                const float* __restrict__ Wout,
                                                const float* __restrict__ bout,
                                                const int* __restrict__ pos,
                                                float* __restrict__ out, int N) {
  int wid = (blockIdx.x * 256 + threadIdx.x) >> 6;
  int lane = threadIdx.x & 63;
  if (wid >= N) return;
  const float2* m2 = (const float2*)m;
  float di = dinv[wid];
  float sl = di * di;
  float2 mv = m2[(size_t)wid * 64 + lane];
  float ax = mv.x * sl, ay = mv.y * sl;   // self-loop contribution
  int e0 = row_start[wid], e1 = row_start[wid + 1];
  for (int base = e0; base < e1; base += 64) {
    int cnt = e1 - base;
    if (cnt > 64) cnt = 64;
    int sL = 0;
    float nL = 0.f;
    if (base + lane < e1) {
      sL = csr_src[base + lane];
      nL = csr_norm[base + lane];
    }
    for (int j = 0; j < cnt; ++j) {
      int s = __shfl(sL, j);
      float nr = __shfl(nL, j);
      float2 v = m2[(size_t)s * 64 + lane];
      ax = fmaf(v.x, nr, ax);
      ay = fmaf(v.y, nr, ay);
    }
  }
  float2 bb = ((const float2*)bias)[lane];
  float2 hv = ((const float2*)h)[(size_t)wid * 64 + lane];
  float rx = fmaxf(ax + bb.x, 0.f) + hv.x;
  float ry = fmaxf(ay + bb.y, 0.f) + hv.y;
  if (FINAL) {
    float2 wv = ((const float2*)Wout)[lane];
    float s = rx * wv.x + ry * wv.y;
#pragma unroll
    for (int off = 32; off > 0; off >>= 1) s += __shfl_down(s, off);
    if (lane == 0) out[pos[wid]] = s + bout[0];
  } else {
    float2* h2 = (float2*)h;
    float2 r;
    r.x = rx;
    r.y = ry;
    h2[(size_t)wid * 64 + lane] = r;
  }
}

// ---------------- launcher ----------------

extern "C" void kernel_launch(void* const* d_in, const int* in_sizes, int n_in,
                              void* d_out, int out_size, void* d_ws, size_t ws_size,
                              hipStream_t stream) {
  const float* x        = (const float*)d_in[0];
  const int*   edge_src = (const int*)d_in[1];
  const int*   edge_dst = (const int*)d_in[2];
  const int*   batch_vec= (const int*)d_in[3];
  const int*   tool_idx = (const int*)d_in[4];
  const int*   query_idx= (const int*)d_in[5];
  const float* W_align  = (const float*)d_in[6];
  const float* b_align  = (const float*)d_in[7];
  const float* W1       = (const float*)d_in[8];
  const float* b1       = (const float*)d_in[9];
  const float* W2       = (const float*)d_in[10];
  const float* b2       = (const float*)d_in[11];
  const float* W_out    = (const float*)d_in[12];
  const float* b_out    = (const float*)d_in[13];

  const int N   = in_sizes[3];
  const int E   = in_sizes[1];
  const int DIN = in_sizes[0] / N;     // 768
  const int n_tool  = in_sizes[4];
  const int n_query = in_sizes[5];
  (void)n_in; (void)out_size; (void)ws_size;

  char* p = (char*)d_ws;
  auto alloc = [&](size_t bytes) {
    void* r = (void*)p;
    p += (bytes + 255) & ~(size_t)255;
    return r;
  };
  int*   degi      = (int*)alloc((size_t)N * 4);
  float* dinv      = (float*)alloc((size_t)N * 4);
  int*   row_start = (int*)alloc((size_t)(N + 1) * 4);
  int*   fillc     = (int*)alloc((size_t)N * 4);
  int*   pos       = (int*)alloc((size_t)N * 4);
  int*   csr_src   = (int*)alloc((size_t)E * 4);
  float* csr_norm  = (float*)alloc((size_t)E * 4);
  float* h         = (float*)alloc((size_t)N * HDIM * 4);
  float* m         = (float*)alloc((size_t)N * HDIM * 4);
  int*   bsum      = (int*)alloc((size_t)1024 * 4);
  u16*   WthA      = (u16*)alloc((size_t)DIN * HDIM * 2);
  u16*   WtlA      = (u16*)alloc((size_t)DIN * HDIM * 2);
  u16*   Wth1      = (u16*)alloc((size_t)HDIM * HDIM * 2);
  u16*   Wtl1      = (u16*)alloc((size_t)HDIM * HDIM * 2);
  u16*   Wth2      = (u16*)alloc((size_t)HDIM * HDIM * 2);
  u16*   Wtl2      = (u16*)alloc((size_t)HDIM * HDIM * 2);

  const int nblkE = (E + 255) / 256;
  const int nblkN = (N + 255) / 256;   // 391 (<=512 required for scan2)

  // CSR build (degi zeroed by our kernel; fillc zeroed inside scan1)
  k_zero<<<nblkN, 256, 0, stream>>>(degi, N);
  k_count<<<nblkE, 256, 0, stream>>>(edge_dst, degi, E);
  k_scan1<<<nblkN, 256, 0, stream>>>(degi, row_start, bsum, dinv, fillc, N);
  k_scan2<<<1, 512, 0, stream>>>(bsum, nblkN);
  k_scan3<<<nblkN, 256, 0, stream>>>(row_start, bsum, N, E);
  k_fill<<<nblkE, 256, 0, stream>>>(edge_src, edge_dst, row_start, fillc, dinv,
                                    csr_src, csr_norm, E);

  // output slot map + batch indices (independent of the above)
  k_posmap<<<(n_tool + n_query + 255) / 256, 256, 0, stream>>>(
      tool_idx, query_idx, batch_vec, pos, (float*)d_out, n_tool, n_query);

  // weight pre-split (tiled hi/lo bf16), one launch for all three
  const int na = DIN * HDIM, n1 = HDIM * HDIM;
  k_split3<<<(na + 2 * n1 + 255) / 256, 256, 0, stream>>>(
      W_align, W1, W2, WthA, WtlA, Wth1, Wtl1, Wth2, Wtl2, na, n1);

  const int gemmBlocks = (N + 127) / 128;
  const int waveBlocks = (N * 64 + 255) / 256;

  // h = x @ W_align + b_align
  k_gemm_bf<768, true><<<gemmBlocks, 256, 0, stream>>>(x, WthA, WtlA, b_align, h, N);

  // layer 1
  k_gemm_bf<128, false><<<gemmBlocks, 256, 0, stream>>>(h, Wth1, Wtl1, nullptr, m, N);
  k_gather<false><<<waveBlocks, 256, 0, stream>>>(m, h, row_start, csr_src, csr_norm,
                                                  dinv, b1, nullptr, nullptr, nullptr,
                                                  nullptr, N);
  // layer 2 + fused output projection
  k_gemm_bf<128, false><<<gemmBlocks, 256, 0, stream>>>(h, Wth2, Wtl2, nullptr, m, N);
  k_gather<true><<<waveBlocks, 256, 0, stream>>>(m, h, row_start, csr_src, csr_norm,
                                                 dinv, b2, W_out, b_out, pos,
                                                 (float*)d_out, N);
}

// Round 10
// 364.026 us; speedup vs baseline: 1.9423x; 1.0080x over previous
//
#include <hip/hip_runtime.h>

// QueryAwareGNN: N=100000, E=600000, DIN=768, H=128, G=100.
// Output (flat f32): tool_logits[99000] | query_logits[1000] | tool_batch_index[99000]

#define HDIM 128

typedef short s16x8 __attribute__((ext_vector_type(8)));
typedef unsigned short u16;
typedef unsigned short u16x8 __attribute__((ext_vector_type(8)));
typedef float f32x4 __attribute__((ext_vector_type(4)));

// split f32 into hi/lo bf16 (truncation hi; lo captures next 8 mantissa bits)
__device__ inline void split2(float f, u16& hi, u16& lo) {
  unsigned u = __builtin_bit_cast(unsigned, f);
  hi = (u16)(u >> 16);
  float fh = __builtin_bit_cast(float, u & 0xFFFF0000u);
  float fl = f - fh;
  lo = (u16)(__builtin_bit_cast(unsigned, fl) >> 16);
}

// round-to-nearest-even f32 -> bf16
__device__ inline u16 bf16rne(float f) {
  unsigned u = __builtin_bit_cast(unsigned, f);
  u += 0x7FFFu + ((u >> 16) & 1u);
  return (u16)(u >> 16);
}

// convert 8 f32 (two f32x4) -> s16x8 of bf16 (RNE)
__device__ inline s16x8 cvt8(f32x4 a, f32x4 b) {
  s16x8 r;
  r[0] = (short)bf16rne(a[0]); r[1] = (short)bf16rne(a[1]);
  r[2] = (short)bf16rne(a[2]); r[3] = (short)bf16rne(a[3]);
  r[4] = (short)bf16rne(b[0]); r[5] = (short)bf16rne(b[1]);
  r[6] = (short)bf16rne(b[2]); r[7] = (short)bf16rne(b[3]);
  return r;
}

// ---------------- prep: zero degi | posmap+batch | weight pre-split ----------------
// One kernel, three independent index segments.
// Weight tiled layout: th[(k/32)][n][k%32] (each k-block = exact 8KB LDS image)

__global__ __launch_bounds__(256) void k_prep(int* __restrict__ degi, int N,
                                              const int* __restrict__ tool_idx,
                                              const int* __restrict__ query_idx,
                                              const int* __restrict__ batch_vec,
                                              int* __restrict__ pos,
                                              float* __restrict__ out,
                                              int n_tool, int n_query,
                                              const float* __restrict__ Wa,
                                              const float* __restrict__ W1,
                                              const float* __restrict__ W2,
                                              u16* __restrict__ tha, u16* __restrict__ tla,
                                              u16* __restrict__ th1, u16* __restrict__ tl1,
                                              u16* __restrict__ th2, u16* __restrict__ tl2,
                                              int na, int n1) {
  int g = blockIdx.x * 256 + threadIdx.x;
  if (g < N) degi[g] = 0;
  int g1 = g - N;
  if (g1 >= 0 && g1 < n_tool) {
    int nd = tool_idx[g1];
    pos[nd] = g1;
    out[n_tool + n_query + g1] = (float)batch_vec[nd];
  } else if (g1 >= n_tool && g1 < n_tool + n_query) {
    int q = g1 - n_tool;
    pos[query_idx[q]] = n_tool + q;
  }
  int g2 = g - N - n_tool - n_query;
  if (g2 >= 0 && g2 < na + 2 * n1) {
    const float* W;
    u16 *th, *tl;
    int idx;
    if (g2 < na) { W = Wa; th = tha; tl = tla; idx = g2; }
    else if (g2 < na + n1) { W = W1; th = th1; tl = tl1; idx = g2 - na; }
    else { W = W2; th = th2; tl = tl2; idx = g2 - na - n1; }
    int n = idx & 127, k = idx >> 7;
    u16 h, l;
    split2(W[idx], h, l);
    int o = ((k >> 5) << 12) | (n << 5) | (k & 31);
    th[o] = h;
    tl[o] = l;
  }
}

// ---------------- CSR build ----------------

__global__ __launch_bounds__(256) void k_count(const int* __restrict__ dst,
                                               int* __restrict__ degi, int E) {
  int g = blockIdx.x * 256 + threadIdx.x;
  if (g < E) atomicAdd(&degi[dst[g]], 1);
}

// scan1: per-256-block exclusive scan; also dinv + fillc-zero (fused)
__global__ __launch_bounds__(256) void k_scan1(const int* __restrict__ in,
                                               int* __restrict__ out,
                                               int* __restrict__ bsum,
                                               float* __restrict__ dinv,
                                               int* __restrict__ fillc, int n) {
  __shared__ int s[256];
  int t = threadIdx.x, g = blockIdx.x * 256 + t;
  int v = (g < n) ? in[g] : 0;
  if (g < n) {
    dinv[g] = rsqrtf((float)(v + 1));  // +1 self-loop
    fillc[g] = 0;
  }
  s[t] = v;
  for (int off = 1; off < 256; off <<= 1) {
    __syncthreads();
    int x = (t >= off) ? s[t - off] : 0;
    __syncthreads();
    s[t] += x;
  }
  if (g < n) out[g] = s[t] - v;
  if (t == 255) bsum[blockIdx.x] = s[255];
}

// scan23: every block re-scans bsum (nb<=512) in LDS and applies its offsets.
__global__ __launch_bounds__(512) void k_scan23(int* __restrict__ row_start,
                                                const int* __restrict__ bsum,
                                                int nb, int n, int total) {
  __shared__ int s[512];
  int t = threadIdx.x;
  int v = (t < nb) ? bsum[t] : 0;
  s[t] = v;
  for (int off = 1; off < 512; off <<= 1) {
    __syncthreads();
    int x = (t >= off) ? s[t - off] : 0;
    __syncthreads();
    s[t] += x;
  }
  __syncthreads();           // s[t] = inclusive prefix of bsum
  int g = blockIdx.x * 512 + t;
  int bi = g >> 8;           // which 256-block this element came from
  int off = (bi == 0) ? 0 : s[bi - 1];
  if (g < n) row_start[g] += off;
  if (g == 0) row_start[n] = total;
}

__global__ __launch_bounds__(256) void k_fill(const int* __restrict__ src,
                                              const int* __restrict__ dst,
                                              const int* __restrict__ row_start,
                                              int* __restrict__ fill,
                                              const float* __restrict__ dinv,
                                              int* __restrict__ csr_src,
                                              float* __restrict__ csr_norm, int E) {
  int g = blockIdx.x * 256 + threadIdx.x;
  if (g < E) {
    int s = src[g], d = dst[g];
    int p = atomicAdd(&fill[d], 1);
    int o = row_start[d] + p;
    csr_src[o] = s;
    csr_norm[o] = dinv[s] * dinv[d];
  }
}

// ---------------- MFMA GEMM: C[M,128] = A[M,K] @ W[K,128] (+bias) ----------------
// A staged in LDS as raw f32 (pad-36 rows = 144B, 16B-aligned, bank-uniform);
// f32->bf16 RNE happens at fragment-load time so the cvt VALU co-issues under
// MFMA (separate pipes). B split hi+lo bf16, pre-tiled, pad-40 rows.
// C = A_bf16*(Bh+Bl): 2 MFMAs/fragment. 128x128 tile, BK=32, 4 waves 2x2.

template <int K, bool BIAS>
__global__ __launch_bounds__(256) void k_gemm_bf(const float* __restrict__ A,
                                                 const u16* __restrict__ Bth,
                                                 const u16* __restrict__ Btl,
                                                 const float* __restrict__ bias,
                                                 float* __restrict__ C, int M) {
  __shared__ float Af[128][36];  // f32 A tile, stride 36 (144B rows)
  __shared__ u16 Bh[128][40];    // B transposed: Bh[n][k], stride 40 (80B rows)
  __shared__ u16 Bl[128][40];

  const int t = threadIdx.x;
  const int m0 = blockIdx.x << 7;
  const int lane = t & 63, w = t >> 6;
  const int wm = (w >> 1) << 6, wn = (w & 1) << 6;
  const int fr = lane & 15;          // row (A) / col (B) within fragment
  const int fk = (lane >> 4) << 3;   // k offset within fragment
  const int srow = t >> 1;           // staging: row 0..127
  const int scol = (t & 1) << 4;     // staging: col 0 or 16

  f32x4 acc[4][4] = {};
  const bool valid = (m0 + srow) < M;
  const float* arow = A + (size_t)(m0 + srow) * K + scol;

  f32x4 v0 = {}, v1 = {}, v2 = {}, v3 = {};
  if (valid) {
    v0 = *(const f32x4*)(arow + 0);
    v1 = *(const f32x4*)(arow + 4);
    v2 = *(const f32x4*)(arow + 8);
    v3 = *(const f32x4*)(arow + 12);
  }

  for (int kb = 0; kb < K; kb += 32) {
    // ---- A stage: 4x ds_write_b128, no conversion
    *(f32x4*)&Af[srow][scol + 0] = v0;
    *(f32x4*)&Af[srow][scol + 4] = v1;
    *(f32x4*)&Af[srow][scol + 8] = v2;
    *(f32x4*)&Af[srow][scol + 12] = v3;

    // ---- B stage: coalesced 32B/thread from pre-tiled weights
    {
      const u16* bsrc = Bth + ((size_t)(kb >> 5) << 12) + (t << 4);
      u16x8 p0 = *(const u16x8*)bsrc;
      u16x8 p1 = *(const u16x8*)(bsrc + 8);
      const u16* bsrc2 = Btl + ((size_t)(kb >> 5) << 12) + (t << 4);
      u16x8 q0 = *(const u16x8*)bsrc2;
      u16x8 q1 = *(const u16x8*)(bsrc2 + 8);
      int bn = t >> 1, bseg = (t & 1) << 4;
      *(u16x8*)&Bh[bn][bseg] = p0;
      *(u16x8*)&Bh[bn][bseg + 8] = p1;
      *(u16x8*)&Bl[bn][bseg] = q0;
      *(u16x8*)&Bl[bn][bseg + 8] = q1;
    }
    __syncthreads();

    // ---- prefetch next A tile into regs (latency hides under MFMA)
    if (valid && kb + 32 < K) {
      const float* ap = arow + kb + 32;
      v0 = *(const f32x4*)(ap + 0);
      v1 = *(const f32x4*)(ap + 4);
      v2 = *(const f32x4*)(ap + 8);
      v3 = *(const f32x4*)(ap + 12);
    }

    // ---- fragments (A cvt here, under MFMA) + 32 MFMAs
    s16x8 ah[4], bh[4], bl[4];
#pragma unroll
    for (int i = 0; i < 4; ++i) {
      const float* ar = &Af[wm + (i << 4) + fr][fk];
      f32x4 a0 = *(const f32x4*)(ar + 0);
      f32x4 a1 = *(const f32x4*)(ar + 4);
      ah[i] = cvt8(a0, a1);
      bh[i] = *(const s16x8*)&Bh[wn + (i << 4) + fr][fk];
      bl[i] = *(const s16x8*)&Bl[wn + (i << 4) + fr][fk];
    }
#pragma unroll
    for (int i = 0; i < 4; ++i)
#pragma unroll
      for (int j = 0; j < 4; ++j) {
        acc[i][j] = __builtin_amdgcn_mfma_f32_16x16x32_bf16(ah[i], bh[j], acc[i][j], 0, 0, 0);
        acc[i][j] = __builtin_amdgcn_mfma_f32_16x16x32_bf16(ah[i], bl[j], acc[i][j], 0, 0, 0);
      }
    __syncthreads();
  }

  // ---- epilogue: C/D layout col=lane&15, row=(lane>>4)*4+reg
  const int cr = (lane >> 4) << 2;
#pragma unroll
  for (int i = 0; i < 4; ++i) {
    int mbase = m0 + wm + (i << 4) + cr;
#pragma unroll
    for (int j = 0; j < 4; ++j) {
      int n = wn + (j << 4) + fr;
      float bv = BIAS ? bias[n] : 0.0f;
#pragma unroll
      for (int r = 0; r < 4; ++r)
        if (mbase + r < M) C[(size_t)(mbase + r) * HDIM + n] = acc[i][j][r] + bv;
    }
  }
}

// ---------------- gather + bias + relu + residual ----------------
// One wave per node. Edge indices/norms loaded 64-at-a-time (coalesced) and
// broadcast via shfl -> m-row gathers are independent back-to-back loads.
// FINAL=true: fuse the output projection (dot W_out, shuffle-reduce, scatter
// to out[pos[node]]) and skip the h write entirely.

template <bool FINAL>
__global__ __launch_bounds__(256) void k_gather(const float* __restrict__ m,
                                                float* __restrict__ h,
                                                const int* __restrict__ row_start,
                                                const int* __restrict__ csr_src,
                                                const float* __restrict__ csr_norm,
                                                const float* __restrict__ dinv,
                                                const float* __restrict__ bias,
                                                const float* __restrict__ Wout,
                                                const float* __restrict__ bout,
                                                const int* __restrict__ pos,
                                                float* __restrict__ out, int N) {
  int wid = (blockIdx.x * 256 + threadIdx.x) >> 6;
  int lane = threadIdx.x & 63;
  if (wid >= N) return;
  const float2* m2 = (const float2*)m;
  float di = dinv[wid];
  float sl = di * di;
  float2 mv = m2[(size_t)wid * 64 + lane];
  float ax = mv.x * sl, ay = mv.y * sl;   // self-loop contribution
  int e0 = row_start[wid], e1 = row_start[wid + 1];
  for (int base = e0; base < e1; base += 64) {
    int cnt = e1 - base;
    if (cnt > 64) cnt = 64;
    int sL = 0;
    float nL = 0.f;
    if (base + lane < e1) {
      sL = csr_src[base + lane];
      nL = csr_norm[base + lane];
    }
    for (int j = 0; j < cnt; ++j) {
      int s = __shfl(sL, j);
      float nr = __shfl(nL, j);
      float2 v = m2[(size_t)s * 64 + lane];
      ax = fmaf(v.x, nr, ax);
      ay = fmaf(v.y, nr, ay);
    }
  }
  float2 bb = ((const float2*)bias)[lane];
  float2 hv = ((const float2*)h)[(size_t)wid * 64 + lane];
  float rx = fmaxf(ax + bb.x, 0.f) + hv.x;
  float ry = fmaxf(ay + bb.y, 0.f) + hv.y;
  if (FINAL) {
    float2 wv = ((const float2*)Wout)[lane];
    float s = rx * wv.x + ry * wv.y;
#pragma unroll
    for (int off = 32; off > 0; off >>= 1) s += __shfl_down(s, off);
    if (lane == 0) out[pos[wid]] = s + bout[0];
  } else {
    float2* h2 = (float2*)h;
    float2 r;
    r.x = rx;
    r.y = ry;
    h2[(size_t)wid * 64 + lane] = r;
  }
}

// ---------------- launcher ----------------

extern "C" void kernel_launch(void* const* d_in, const int* in_sizes, int n_in,
                              void* d_out, int out_size, void* d_ws, size_t ws_size,
                              hipStream_t stream) {
  const float* x        = (const float*)d_in[0];
  const int*   edge_src = (const int*)d_in[1];
  const int*   edge_dst = (const int*)d_in[2];
  const int*   batch_vec= (const int*)d_in[3];
  const int*   tool_idx = (const int*)d_in[4];
  const int*   query_idx= (const int*)d_in[5];
  const float* W_align  = (const float*)d_in[6];
  const float* b_align  = (const float*)d_in[7];
  const float* W1       = (const float*)d_in[8];
  const float* b1       = (const float*)d_in[9];
  const float* W2       = (const float*)d_in[10];
  const float* b2       = (const float*)d_in[11];
  const float* W_out    = (const float*)d_in[12];
  const float* b_out    = (const float*)d_in[13];

  const int N   = in_sizes[3];
  const int E   = in_sizes[1];
  const int DIN = in_sizes[0] / N;     // 768
  const int n_tool  = in_sizes[4];
  const int n_query = in_sizes[5];
  (void)n_in; (void)out_size; (void)ws_size;

  char* p = (char*)d_ws;
  auto alloc = [&](size_t bytes) {
    void* r = (void*)p;
    p += (bytes + 255) & ~(size_t)255;
    return r;
  };
  int*   degi      = (int*)alloc((size_t)N * 4);
  float* dinv      = (float*)alloc((size_t)N * 4);
  int*   row_start = (int*)alloc((size_t)(N + 1) * 4);
  int*   fillc     = (int*)alloc((size_t)N * 4);
  int*   pos       = (int*)alloc((size_t)N * 4);
  int*   csr_src   = (int*)alloc((size_t)E * 4);
  float* csr_norm  = (float*)alloc((size_t)E * 4);
  float* h         = (float*)alloc((size_t)N * HDIM * 4);
  float* m         = (float*)alloc((size_t)N * HDIM * 4);
  int*   bsum      = (int*)alloc((size_t)1024 * 4);
  u16*   WthA      = (u16*)alloc((size_t)DIN * HDIM * 2);
  u16*   WtlA      = (u16*)alloc((size_t)DIN * HDIM * 2);
  u16*   Wth1      = (u16*)alloc((size_t)HDIM * HDIM * 2);
  u16*   Wtl1      = (u16*)alloc((size_t)HDIM * HDIM * 2);
  u16*   Wth2      = (u16*)alloc((size_t)HDIM * HDIM * 2);
  u16*   Wtl2      = (u16*)alloc((size_t)HDIM * HDIM * 2);

  const int nblkE = (E + 255) / 256;
  const int nblkN = (N + 255) / 256;   // 391 (<=512 required for scan23)
  const int na = DIN * HDIM, n1 = HDIM * HDIM;

  // prep: zero degi | posmap+batch | weight pre-split (one kernel)
  const int prepWork = N + n_tool + n_query + na + 2 * n1;
  k_prep<<<(prepWork + 255) / 256, 256, 0, stream>>>(
      degi, N, tool_idx, query_idx, batch_vec, pos, (float*)d_out, n_tool, n_query,
      W_align, W1, W2, WthA, WtlA, Wth1, Wtl1, Wth2, Wtl2, na, n1);

  // CSR build
  k_count<<<nblkE, 256, 0, stream>>>(edge_dst, degi, E);
  k_scan1<<<nblkN, 256, 0, stream>>>(degi, row_start, bsum, dinv, fillc, N);
  k_scan23<<<(N + 511) / 512, 512, 0, stream>>>(row_start, bsum, nblkN, N, E);
  k_fill<<<nblkE, 256, 0, stream>>>(edge_src, edge_dst, row_start, fillc, dinv,
                                    csr_src, csr_norm, E);

  const int gemmBlocks = (N + 127) / 128;
  const int waveBlocks = (N * 64 + 255) / 256;

  // h = x @ W_align + b_align
  k_gemm_bf<768, true><<<gemmBlocks, 256, 0, stream>>>(x, WthA, WtlA, b_align, h, N);

  // layer 1
  k_gemm_bf<128, false><<<gemmBlocks, 256, 0, stream>>>(h, Wth1, Wtl1, nullptr, m, N);
  k_gather<false><<<waveBlocks, 256, 0, stream>>>(m, h, row_start, csr_src, csr_norm,
                                                  dinv, b1, nullptr, nullptr, nullptr,
                                                  nullptr, N);
  // layer 2 + fused output projection
  k_gemm_bf<128, false><<<gemmBlocks, 256, 0, stream>>>(h, Wth2, Wtl2, nullptr, m, N);
  k_gather<true><<<waveBlocks, 256, 0, stream>>>(m, h, row_start, csr_src, csr_norm,
                                                 dinv, b2, W_out, b_out, pos,
                                                 (float*)d_out, N);
}

// Round 12
// 343.884 us; speedup vs baseline: 2.0561x; 1.0586x over previous
//
#include <hip/hip_runtime.h>
#include <hip/hip_fp16.h>

// QueryAwareGNN: N=100000, E=600000, DIN=768, H=128, G=100.
// Output (flat f32): tool_logits[99000] | query_logits[1000] | tool_batch_index[99000]

#define HDIM 128

typedef short s16x8 __attribute__((ext_vector_type(8)));
typedef unsigned short u16;
typedef unsigned short u16x8 __attribute__((ext_vector_type(8)));
typedef float f32x4 __attribute__((ext_vector_type(4)));

// split f32 into hi/lo bf16 (truncation hi; lo captures next 8 mantissa bits)
__device__ inline void split2(float f, u16& hi, u16& lo) {
  unsigned u = __builtin_bit_cast(unsigned, f);
  hi = (u16)(u >> 16);
  float fh = __builtin_bit_cast(float, u & 0xFFFF0000u);
  float fl = f - fh;
  lo = (u16)(__builtin_bit_cast(unsigned, fl) >> 16);
}

// round-to-nearest-even f32 -> bf16
__device__ inline u16 bf16rne(float f) {
  unsigned u = __builtin_bit_cast(unsigned, f);
  u += 0x7FFFu + ((u >> 16) & 1u);
  return (u16)(u >> 16);
}

// convert 8 f32 (two f32x4) -> s16x8 of bf16 (RNE)
__device__ inline s16x8 cvt8(f32x4 a, f32x4 b) {
  s16x8 r;
  r[0] = (short)bf16rne(a[0]); r[1] = (short)bf16rne(a[1]);
  r[2] = (short)bf16rne(a[2]); r[3] = (short)bf16rne(a[3]);
  r[4] = (short)bf16rne(b[0]); r[5] = (short)bf16rne(b[1]);
  r[6] = (short)bf16rne(b[2]); r[7] = (short)bf16rne(b[3]);
  return r;
}

// ---------------- prep: zero degi | posmap+batch | weight pre-split ----------------
// One kernel, three independent index segments.
// Weight tiled layout: th[(k/32)][n][k%32] (each k-block = exact 8KB LDS image)

__global__ __launch_bounds__(256) void k_prep(int* __restrict__ degi, int N,
                                              const int* __restrict__ tool_idx,
                                              const int* __restrict__ query_idx,
                                              const int* __restrict__ batch_vec,
                                              int* __restrict__ pos,
                                              float* __restrict__ out,
                                              int n_tool, int n_query,
                                              const float* __restrict__ Wa,
                                              const float* __restrict__ W1,
                                              const float* __restrict__ W2,
                                              u16* __restrict__ tha, u16* __restrict__ tla,
                                              u16* __restrict__ th1, u16* __restrict__ tl1,
                                              u16* __restrict__ th2, u16* __restrict__ tl2,
                                              int na, int n1) {
  int g = blockIdx.x * 256 + threadIdx.x;
  if (g < N) degi[g] = 0;
  int g1 = g - N;
  if (g1 >= 0 && g1 < n_tool) {
    int nd = tool_idx[g1];
    pos[nd] = g1;
    out[n_tool + n_query + g1] = (float)batch_vec[nd];
  } else if (g1 >= n_tool && g1 < n_tool + n_query) {
    int q = g1 - n_tool;
    pos[query_idx[q]] = n_tool + q;
  }
  int g2 = g - N - n_tool - n_query;
  if (g2 >= 0 && g2 < na + 2 * n1) {
    const float* W;
    u16 *th, *tl;
    int idx;
    if (g2 < na) { W = Wa; th = tha; tl = tla; idx = g2; }
    else if (g2 < na + n1) { W = W1; th = th1; tl = tl1; idx = g2 - na; }
    else { W = W2; th = th2; tl = tl2; idx = g2 - na - n1; }
    int n = idx & 127, k = idx >> 7;
    u16 h, l;
    split2(W[idx], h, l);
    int o = ((k >> 5) << 12) | (n << 5) | (k & 31);
    th[o] = h;
    tl[o] = l;
  }
}

// ---------------- CSR build ----------------

__global__ __launch_bounds__(256) void k_count(const int* __restrict__ dst,
                                               int* __restrict__ degi, int E) {
  int g = blockIdx.x * 256 + threadIdx.x;
  if (g < E) atomicAdd(&degi[dst[g]], 1);
}

// scan1: per-256-block exclusive scan; also dinv (fused)
__global__ __launch_bounds__(256) void k_scan1(const int* __restrict__ in,
                                               int* __restrict__ out,
                                               int* __restrict__ bsum,
                                               float* __restrict__ dinv, int n) {
  __shared__ int s[256];
  int t = threadIdx.x, g = blockIdx.x * 256 + t;
  int v = (g < n) ? in[g] : 0;
  if (g < n) dinv[g] = rsqrtf((float)(v + 1));  // +1 self-loop
  s[t] = v;
  for (int off = 1; off < 256; off <<= 1) {
    __syncthreads();
    int x = (t >= off) ? s[t - off] : 0;
    __syncthreads();
    s[t] += x;
  }
  if (g < n) out[g] = s[t] - v;
  if (t == 255) bsum[blockIdx.x] = s[255];
}

// scan23: every block re-scans bsum (nb<=512) in LDS and applies its offsets.
__global__ __launch_bounds__(512) void k_scan23(int* __restrict__ row_start,
                                                const int* __restrict__ bsum,
                                                int nb, int n, int total) {
  __shared__ int s[512];
  int t = threadIdx.x;
  int v = (t < nb) ? bsum[t] : 0;
  s[t] = v;
  for (int off = 1; off < 512; off <<= 1) {
    __syncthreads();
    int x = (t >= off) ? s[t - off] : 0;
    __syncthreads();
    s[t] += x;
  }
  __syncthreads();           // s[t] = inclusive prefix of bsum
  int g = blockIdx.x * 512 + t;
  int bi = g >> 8;           // which 256-block this element came from
  int off = (bi == 0) ? 0 : s[bi - 1];
  if (g < n) row_start[g] += off;
  if (g == 0) row_start[n] = total;
}

// fill: claims slots by decrementing degi (dead after scan1) -> no fillc buffer.
__global__ __launch_bounds__(256) void k_fill(const int* __restrict__ src,
                                              const int* __restrict__ dst,
                                              const int* __restrict__ row_start,
                                              int* __restrict__ degi,
                                              const float* __restrict__ dinv,
                                              int* __restrict__ csr_src,
                                              float* __restrict__ csr_norm, int E) {
  int g = blockIdx.x * 256 + threadIdx.x;
  if (g < E) {
    int s = src[g], d = dst[g];
    int p = atomicSub(&degi[d], 1) - 1;   // deg-1 .. 0, unique per edge
    int o = row_start[d] + p;
    csr_src[o] = s;
    csr_norm[o] = dinv[s] * dinv[d];
  }
}

// ---------------- MFMA GEMM: C[M,128] = A[M,K] @ W[K,128] (+bias) ----------------
// A staged in LDS as raw f32 (pad-36 rows); f32->bf16 RNE at fragment-load time
// (cvt co-issues under MFMA). B split hi+lo bf16, pre-tiled, pad-40 rows.
// C = A_bf16*(Bh+Bl): 2 MFMAs/fragment. 128x128 tile, BK=32, 4 waves 2x2.
// OUTH: write C as fp16 (RNE) -- used for the m buffer to halve gather traffic.

template <int K, bool BIAS, bool OUTH>
__global__ __launch_bounds__(256) void k_gemm_bf(const float* __restrict__ A,
                                                 const u16* __restrict__ Bth,
                                                 const u16* __restrict__ Btl,
                                                 const float* __restrict__ bias,
                                                 void* __restrict__ Cv, int M) {
  __shared__ float Af[128][36];  // f32 A tile, stride 36 (144B rows)
  __shared__ u16 Bh[128][40];    // B transposed: Bh[n][k], stride 40 (80B rows)
  __shared__ u16 Bl[128][40];

  const int t = threadIdx.x;
  const int m0 = blockIdx.x << 7;
  const int lane = t & 63, w = t >> 6;
  const int wm = (w >> 1) << 6, wn = (w & 1) << 6;
  const int fr = lane & 15;          // row (A) / col (B) within fragment
  const int fk = (lane >> 4) << 3;   // k offset within fragment
  const int srow = t >> 1;           // staging: row 0..127
  const int scol = (t & 1) << 4;     // staging: col 0 or 16

  f32x4 acc[4][4] = {};
  const bool valid = (m0 + srow) < M;
  const float* arow = A + (size_t)(m0 + srow) * K + scol;

  f32x4 v0 = {}, v1 = {}, v2 = {}, v3 = {};
  if (valid) {
    v0 = *(const f32x4*)(arow + 0);
    v1 = *(const f32x4*)(arow + 4);
    v2 = *(const f32x4*)(arow + 8);
    v3 = *(const f32x4*)(arow + 12);
  }

  for (int kb = 0; kb < K; kb += 32) {
    // ---- A stage: 4x ds_write_b128, no conversion
    *(f32x4*)&Af[srow][scol + 0] = v0;
    *(f32x4*)&Af[srow][scol + 4] = v1;
    *(f32x4*)&Af[srow][scol + 8] = v2;
    *(f32x4*)&Af[srow][scol + 12] = v3;

    // ---- B stage: coalesced 32B/thread from pre-tiled weights
    {
      const u16* bsrc = Bth + ((size_t)(kb >> 5) << 12) + (t << 4);
      u16x8 p0 = *(const u16x8*)bsrc;
      u16x8 p1 = *(const u16x8*)(bsrc + 8);
      const u16* bsrc2 = Btl + ((size_t)(kb >> 5) << 12) + (t << 4);
      u16x8 q0 = *(const u16x8*)bsrc2;
      u16x8 q1 = *(const u16x8*)(bsrc2 + 8);
      int bn = t >> 1, bseg = (t & 1) << 4;
      *(u16x8*)&Bh[bn][bseg] = p0;
      *(u16x8*)&Bh[bn][bseg + 8] = p1;
      *(u16x8*)&Bl[bn][bseg] = q0;
      *(u16x8*)&Bl[bn][bseg + 8] = q1;
    }
    __syncthreads();

    // ---- prefetch next A tile into regs (latency hides under MFMA)
    if (valid && kb + 32 < K) {
      const float* ap = arow + kb + 32;
      v0 = *(const f32x4*)(ap + 0);
      v1 = *(const f32x4*)(ap + 4);
      v2 = *(const f32x4*)(ap + 8);
      v3 = *(const f32x4*)(ap + 12);
    }

    // ---- fragments (A cvt here, under MFMA) + 32 MFMAs
    s16x8 ah[4], bh[4], bl[4];
#pragma unroll
    for (int i = 0; i < 4; ++i) {
      const float* ar = &Af[wm + (i << 4) + fr][fk];
      f32x4 a0 = *(const f32x4*)(ar + 0);
      f32x4 a1 = *(const f32x4*)(ar + 4);
      ah[i] = cvt8(a0, a1);
      bh[i] = *(const s16x8*)&Bh[wn + (i << 4) + fr][fk];
      bl[i] = *(const s16x8*)&Bl[wn + (i << 4) + fr][fk];
    }
#pragma unroll
    for (int i = 0; i < 4; ++i)
#pragma unroll
      for (int j = 0; j < 4; ++j) {
        acc[i][j] = __builtin_amdgcn_mfma_f32_16x16x32_bf16(ah[i], bh[j], acc[i][j], 0, 0, 0);
        acc[i][j] = __builtin_amdgcn_mfma_f32_16x16x32_bf16(ah[i], bl[j], acc[i][j], 0, 0, 0);
      }
    __syncthreads();
  }

  // ---- epilogue: C/D layout col=lane&15, row=(lane>>4)*4+reg
  const int cr = (lane >> 4) << 2;
#pragma unroll
  for (int i = 0; i < 4; ++i) {
    int mbase = m0 + wm + (i << 4) + cr;
#pragma unroll
    for (int j = 0; j < 4; ++j) {
      int n = wn + (j << 4) + fr;
      float bv = BIAS ? bias[n] : 0.0f;
#pragma unroll
      for (int r = 0; r < 4; ++r) {
        if (mbase + r < M) {
          if (OUTH) {
            ((__half*)Cv)[(size_t)(mbase + r) * HDIM + n] =
                __float2half_rn(acc[i][j][r] + bv);
          } else {
            ((float*)Cv)[(size_t)(mbase + r) * HDIM + n] = acc[i][j][r] + bv;
          }
        }
      }
    }
  }
}

// ---------------- gather + bias + relu + residual ----------------
// One wave per node; m is fp16 (256B/row gathers). Edge indices/norms loaded
// 64-at-a-time (coalesced) and broadcast via shfl -> m-row gathers are
// independent back-to-back loads. All arithmetic f32.
// FINAL=true: fuse output projection and skip the h write.

template <bool FINAL>
__global__ __launch_bounds__(256) void k_gather(const __half2* __restrict__ m2,
                                                float* __restrict__ h,
                                                const int* __restrict__ row_start,
                                                const int* __restrict__ csr_src,
                                                const float* __restrict__ csr_norm,
                                                const float* __restrict__ dinv,
                                                const float* __restrict__ bias,
                                                const float* __restrict__ Wout,
                                                const float* __restrict__ bout,
                                                const int* __restrict__ pos,
                                                float* __restrict__ out, int N) {
  int wid = (blockIdx.x * 256 + threadIdx.x) >> 6;
  int lane = threadIdx.x & 63;
  if (wid >= N) return;
  float di = dinv[wid];
  float sl = di * di;
  float2 mv = __half22float2(m2[(size_t)wid * 64 + lane]);
  float ax = mv.x * sl, ay = mv.y * sl;   // self-loop contribution
  int e0 = row_start[wid], e1 = row_start[wid + 1];
  for (int base = e0; base < e1; base += 64) {
    int cnt = e1 - base;
    if (cnt > 64) cnt = 64;
    int sL = 0;
    float nL = 0.f;
    if (base + lane < e1) {
      sL = csr_src[base + lane];
      nL = csr_norm[base + lane];
    }
    for (int j = 0; j < cnt; ++j) {
      int s = __shfl(sL, j);
      float nr = __shfl(nL, j);
      float2 v = __half22float2(m2[(size_t)s * 64 + lane]);
      ax = fmaf(v.x, nr, ax);
      ay = fmaf(v.y, nr, ay);
    }
  }
  float2 bb = ((const float2*)bias)[lane];
  float2 hv = ((const float2*)h)[(size_t)wid * 64 + lane];
  float rx = fmaxf(ax + bb.x, 0.f) + hv.x;
  float ry = fmaxf(ay + bb.y, 0.f) + hv.y;
  if (FINAL) {
    float2 wv = ((const float2*)Wout)[lane];
    float s = rx * wv.x + ry * wv.y;
#pragma unroll
    for (int off = 32; off > 0; off >>= 1) s += __shfl_down(s, off);
    if (lane == 0) out[pos[wid]] = s + bout[0];
  } else {
    float2* h2 = (float2*)h;
    float2 r;
    r.x = rx;
    r.y = ry;
    h2[(size_t)wid * 64 + lane] = r;
  }
}

// ---------------- launcher ----------------

extern "C" void kernel_launch(void* const* d_in, const int* in_sizes, int n_in,
                              void* d_out, int out_size, void* d_ws, size_t ws_size,
                              hipStream_t stream) {
  const float* x        = (const float*)d_in[0];
  const int*   edge_src = (const int*)d_in[1];
  const int*   edge_dst = (const int*)d_in[2];
  const int*   batch_vec= (const int*)d_in[3];
  const int*   tool_idx = (const int*)d_in[4];
  const int*   query_idx= (const int*)d_in[5];
  const float* W_align  = (const float*)d_in[6];
  const float* b_align  = (const float*)d_in[7];
  const float* W1       = (const float*)d_in[8];
  const float* b1       = (const float*)d_in[9];
  const float* W2       = (const float*)d_in[10];
  const float* b2       = (const float*)d_in[11];
  const float* W_out    = (const float*)d_in[12];
  const float* b_out    = (const float*)d_in[13];

  const int N   = in_sizes[3];
  const int E   = in_sizes[1];
  const int DIN = in_sizes[0] / N;     // 768
  const int n_tool  = in_sizes[4];
  const int n_query = in_sizes[5];
  (void)n_in; (void)out_size; (void)ws_size;

  char* p = (char*)d_ws;
  auto alloc = [&](size_t bytes) {
    void* r = (void*)p;
    p += (bytes + 255) & ~(size_t)255;
    return r;
  };
  int*   degi      = (int*)alloc((size_t)N * 4);
  float* dinv      = (float*)alloc((size_t)N * 4);
  int*   row_start = (int*)alloc((size_t)(N + 1) * 4);
  int*   pos       = (int*)alloc((size_t)N * 4);
  int*   csr_src   = (int*)alloc((size_t)E * 4);
  float* csr_norm  = (float*)alloc((size_t)E * 4);
  float* h         = (float*)alloc((size_t)N * HDIM * 4);
  __half* m        = (__half*)alloc((size_t)N * HDIM * 2);
  int*   bsum      = (int*)alloc((size_t)1024 * 4);
  u16*   WthA      = (u16*)alloc((size_t)DIN * HDIM * 2);
  u16*   WtlA      = (u16*)alloc((size_t)DIN * HDIM * 2);
  u16*   Wth1      = (u16*)alloc((size_t)HDIM * HDIM * 2);
  u16*   Wtl1      = (u16*)alloc((size_t)HDIM * HDIM * 2);
  u16*   Wth2      = (u16*)alloc((size_t)HDIM * HDIM * 2);
  u16*   Wtl2      = (u16*)alloc((size_t)HDIM * HDIM * 2);

  const int nblkE = (E + 255) / 256;
  const int nblkN = (N + 255) / 256;   // 391 (<=512 required for scan23)
  const int na = DIN * HDIM, n1 = HDIM * HDIM;

  // prep: zero degi | posmap+batch | weight pre-split (one kernel)
  const int prepWork = N + n_tool + n_query + na + 2 * n1;
  k_prep<<<(prepWork + 255) / 256, 256, 0, stream>>>(
      degi, N, tool_idx, query_idx, batch_vec, pos, (float*)d_out, n_tool, n_query,
      W_align, W1, W2, WthA, WtlA, Wth1, Wtl1, Wth2, Wtl2, na, n1);

  // CSR build
  k_count<<<nblkE, 256, 0, stream>>>(edge_dst, degi, E);
  k_scan1<<<nblkN, 256, 0, stream>>>(degi, row_start, bsum, dinv, N);
  k_scan23<<<(N + 511) / 512, 512, 0, stream>>>(row_start, bsum, nblkN, N, E);
  k_fill<<<nblkE, 256, 0, stream>>>(edge_src, edge_dst, row_start, degi, dinv,
                                    csr_src, csr_norm, E);

  const int gemmBlocks = (N + 127) / 128;
  const int waveBlocks = (N * 64 + 255) / 256;

  // h = x @ W_align + b_align  (f32 out)
  k_gemm_bf<768, true, false><<<gemmBlocks, 256, 0, stream>>>(
      x, WthA, WtlA, b_align, h, N);

  // layer 1 (m as fp16)
  k_gemm_bf<128, false, true><<<gemmBlocks, 256, 0, stream>>>(
      h, Wth1, Wtl1, nullptr, m, N);
  k_gather<false><<<waveBlocks, 256, 0, stream>>>(
      (const __half2*)m, h, row_start, csr_src, csr_norm, dinv, b1,
      nullptr, nullptr, nullptr, nullptr, N);
  // layer 2 + fused output projection
  k_gemm_bf<128, false, true><<<gemmBlocks, 256, 0, stream>>>(
      h, Wth2, Wtl2, nullptr, m, N);
  k_gather<true><<<waveBlocks, 256, 0, stream>>>(
      (const __half2*)m, h, row_start, csr_src, csr_norm, dinv, b2,
      W_out, b_out, pos, (float*)d_out, N);
}